// Round 4
// baseline (1116.170 us; speedup 1.0000x reference)
//
#include <hip/hip_runtime.h>
#include <hip/hip_bf16.h>
#include <math.h>

// GCN: h1 = relu(Agg(x@W1) + b1); h2 = relu(Agg(h1@W2) + b2);
// out[g] = mean_pool(h2)[g] @ Wf + bf
// Agg uses symmetric deg^-1/2 norm with self-loops (PyG GCNConv default).
// Strategy: build CSR (by dst) once per call, pull-based aggregation (no fp atomics).

#define DFEAT 128

__global__ void k_zero2(int* __restrict__ a, int* __restrict__ b, int n) {
    int i = blockIdx.x * blockDim.x + threadIdx.x;
    if (i < n) { a[i] = 0; b[i] = 0; }
}

__global__ void k_degcount(const int* __restrict__ dst, int* __restrict__ degcnt, int E) {
    int e = blockIdx.x * blockDim.x + threadIdx.x;
    if (e < E) atomicAdd(&degcnt[dst[e]], 1);
}

// Single-block exclusive scan of degcnt[0..N) -> rowptr[0..N]
__global__ __launch_bounds__(1024) void k_scan(const int* __restrict__ degcnt,
                                               int* __restrict__ rowptr, int N) {
    __shared__ int lds[1024];
    int tid = threadIdx.x;
    int chunk = (N + 1023) >> 10;
    int beg = tid * chunk;
    int end = min(beg + chunk, N);
    int s = 0;
    for (int i = beg; i < end; ++i) s += degcnt[i];
    lds[tid] = s;
    __syncthreads();
    // Hillis-Steele inclusive scan (read / sync / write / sync)
    for (int off = 1; off < 1024; off <<= 1) {
        int v = (tid >= off) ? lds[tid - off] : 0;
        __syncthreads();
        lds[tid] += v;
        __syncthreads();
    }
    int run = (tid == 0) ? 0 : lds[tid - 1];  // exclusive base for this chunk
    for (int i = beg; i < end; ++i) { rowptr[i] = run; run += degcnt[i]; }
    if (beg < N && end == N) rowptr[N] = run;  // == E
}

__global__ void k_dinv(const int* __restrict__ degcnt, float* __restrict__ dinv, int N) {
    int i = blockIdx.x * blockDim.x + threadIdx.x;
    if (i < N) dinv[i] = rsqrtf((float)(degcnt[i] + 1));  // +1 self-loop, deg>=1 always
}

__global__ void k_fill(const int* __restrict__ src, const int* __restrict__ dst,
                       const int* __restrict__ rowptr, int* __restrict__ fill,
                       int* __restrict__ col, int E) {
    int e = blockIdx.x * blockDim.x + threadIdx.x;
    if (e < E) {
        int d = dst[e];
        int pos = rowptr[d] + atomicAdd(&fill[d], 1);
        col[pos] = src[e];
    }
}

// C[N,128] = H[N,128] @ W[128,128], f32, W staged in LDS.
// 256 thr: thread -> cols (tid&31)*4..+3, rows (tid>>5)*4..+3 of a 32-row tile.
__global__ __launch_bounds__(256, 2) void k_linear(const float* __restrict__ H,
                                                   const float* __restrict__ W,
                                                   float* __restrict__ C, int N) {
    __shared__ float Wl[128 * 128];   // 64 KB
    __shared__ float inS[32 * 128];   // 16 KB
    int tid = threadIdx.x;
    {   // stage W once per block
        const float4* W4 = (const float4*)W;
        float4* Wl4 = (float4*)Wl;
#pragma unroll
        for (int j = 0; j < 16; ++j) Wl4[tid + j * 256] = W4[tid + j * 256];
    }
    int cg = tid & 31;       // col quad index: cols cg*4..cg*4+3
    int r0 = (tid >> 5) * 4; // rows r0..r0+3 within tile
    int ntiles = (N + 31) >> 5;
    const float4* WL4 = (const float4*)Wl;
    for (int tile = blockIdx.x; tile < ntiles; tile += gridDim.x) {
        int rbase = tile * 32;
        __syncthreads();
        {   // stage 32 input rows (contiguous 16 KB)
            const float4* H4 = (const float4*)(H + (size_t)rbase * DFEAT);
            float4* I4 = (float4*)inS;
            int lim = (N - rbase) * 32;  // avail float4s
#pragma unroll
            for (int j = 0; j < 4; ++j) {
                int idx = tid + j * 256;
                float4 v = make_float4(0.f, 0.f, 0.f, 0.f);
                if (idx < lim) v = H4[idx];
                I4[idx] = v;
            }
        }
        __syncthreads();
        float4 a0 = {0,0,0,0}, a1 = {0,0,0,0}, a2 = {0,0,0,0}, a3 = {0,0,0,0};
#pragma unroll 4
        for (int k = 0; k < 128; ++k) {
            float4 w = WL4[k * 32 + cg];
            float x0 = inS[(r0 + 0) * 128 + k];
            float x1 = inS[(r0 + 1) * 128 + k];
            float x2 = inS[(r0 + 2) * 128 + k];
            float x3 = inS[(r0 + 3) * 128 + k];
            a0.x += x0 * w.x; a0.y += x0 * w.y; a0.z += x0 * w.z; a0.w += x0 * w.w;
            a1.x += x1 * w.x; a1.y += x1 * w.y; a1.z += x1 * w.z; a1.w += x1 * w.w;
            a2.x += x2 * w.x; a2.y += x2 * w.y; a2.z += x2 * w.z; a2.w += x2 * w.w;
            a3.x += x3 * w.x; a3.y += x3 * w.y; a3.z += x3 * w.z; a3.w += x3 * w.w;
        }
        int row = rbase + r0;
        if (row + 0 < N) ((float4*)(C + (size_t)(row + 0) * DFEAT))[cg] = a0;
        if (row + 1 < N) ((float4*)(C + (size_t)(row + 1) * DFEAT))[cg] = a1;
        if (row + 2 < N) ((float4*)(C + (size_t)(row + 2) * DFEAT))[cg] = a2;
        if (row + 3 < N) ((float4*)(C + (size_t)(row + 3) * DFEAT))[cg] = a3;
    }
}

// Pull aggregation: one 64-lane wave per node, float2 per lane.
// hout[i] = relu( dinv[i]^2 * t[i] + sum_{s in inedges(i)} dinv[s]*dinv[i]*t[s] + b )
__global__ __launch_bounds__(256) void k_agg(const float2* __restrict__ T2,
                                             float2* __restrict__ Hout,
                                             const int* __restrict__ col,
                                             const int* __restrict__ rowptr,
                                             const float* __restrict__ dinv,
                                             const float* __restrict__ bias, int N) {
    int lane = threadIdx.x & 63;
    int node = blockIdx.x * 4 + (threadIdx.x >> 6);
    if (node >= N) return;
    float2 b = ((const float2*)bias)[lane];
    float di = dinv[node];
    float2 self = T2[(size_t)node * 64 + lane];
    float ws = di * di;
    float2 acc;
    acc.x = self.x * ws;
    acc.y = self.y * ws;
    int beg = rowptr[node], end = rowptr[node + 1];
    if (beg < end) {
        int s_next = col[beg];
        for (int j = beg; j < end; ++j) {
            int s = s_next;
            if (j + 1 < end) s_next = col[j + 1];   // prefetch next col id
            float w = dinv[s] * di;
            float2 v = T2[(size_t)s * 64 + lane];
            acc.x += w * v.x;
            acc.y += w * v.y;
        }
    }
    acc.x = fmaxf(acc.x + b.x, 0.f);
    acc.y = fmaxf(acc.y + b.y, 0.f);
    Hout[(size_t)node * 64 + lane] = acc;
}

// One block per graph: binary search range in sorted batch, mean-pool, dot Wf, +bf.
__global__ __launch_bounds__(128) void k_pool(const float* __restrict__ Hn,
                                              const int* __restrict__ batch,
                                              const float* __restrict__ Wf,
                                              const float* __restrict__ bf,
                                              float* __restrict__ out, int N) {
    int g = blockIdx.x;
    int tid = threadIdx.x;
    int lo, hi;
    {   // lower_bound(g), lower_bound(g+1)
        int l = 0, h = N;
        while (l < h) { int m = (l + h) >> 1; if (batch[m] < g) l = m + 1; else h = m; }
        lo = l;
        h = N;
        while (l < h) { int m = (l + h) >> 1; if (batch[m] < g + 1) l = m + 1; else h = m; }
        hi = l;
    }
    float sum = 0.f;
    for (int i = lo; i < hi; ++i) sum += Hn[(size_t)i * DFEAT + tid];
    float cnt = (float)((hi - lo) > 0 ? (hi - lo) : 1);
    float val = (sum / cnt) * Wf[tid];
    for (int off = 32; off >= 1; off >>= 1) val += __shfl_down(val, off, 64);
    __shared__ float wsum[2];
    if ((tid & 63) == 0) wsum[tid >> 6] = val;
    __syncthreads();
    if (tid == 0) out[g] = wsum[0] + wsum[1] + bf[0];
}

extern "C" void kernel_launch(void* const* d_in, const int* in_sizes, int n_in,
                              void* d_out, int out_size, void* d_ws, size_t ws_size,
                              hipStream_t stream) {
    const float* x    = (const float*)d_in[0];
    const int*   ei   = (const int*)d_in[1];
    const int*   batch= (const int*)d_in[2];
    const float* W1   = (const float*)d_in[3];
    const float* b1   = (const float*)d_in[4];
    const float* W2   = (const float*)d_in[5];
    const float* b2   = (const float*)d_in[6];
    const float* Wf   = (const float*)d_in[7];
    const float* bf   = (const float*)d_in[8];

    int N = in_sizes[0] / DFEAT;
    int E = in_sizes[1] / 2;
    int G = out_size;  // num_graphs

    const int* src = ei;
    const int* dst = ei + E;

    // workspace partition (256B aligned)
    char* wsb = (char*)d_ws;
    size_t off = 0;
    auto walloc = [&](size_t bytes) {
        void* p = wsb + off;
        off = (off + bytes + 255) & ~(size_t)255;
        return p;
    };
    float* A      = (float*)walloc((size_t)N * DFEAT * sizeof(float)); // 51.2 MB
    float* B      = (float*)walloc((size_t)N * DFEAT * sizeof(float)); // 51.2 MB
    float* dinv   = (float*)walloc((size_t)N * sizeof(float));
    int*   rowptr = (int*)  walloc((size_t)(N + 1) * sizeof(int));
    int*   col    = (int*)  walloc((size_t)E * sizeof(int));           // 6.4 MB
    int*   degcnt = (int*)  walloc((size_t)N * sizeof(int));
    int*   fill   = (int*)  walloc((size_t)N * sizeof(int));
    (void)ws_size; (void)n_in;

    int gN = (N + 255) / 256;
    int gE = (E + 255) / 256;

    // CSR build
    k_zero2<<<gN, 256, 0, stream>>>(degcnt, fill, N);
    k_degcount<<<gE, 256, 0, stream>>>(dst, degcnt, E);
    k_scan<<<1, 1024, 0, stream>>>(degcnt, rowptr, N);
    k_dinv<<<gN, 256, 0, stream>>>(degcnt, dinv, N);
    k_fill<<<gE, 256, 0, stream>>>(src, dst, rowptr, fill, col, E);

    // layer 1
    k_linear<<<512, 256, 0, stream>>>(x, W1, A, N);
    k_agg<<<(N + 3) / 4, 256, 0, stream>>>((const float2*)A, (float2*)B, col, rowptr, dinv, b1, N);
    // layer 2
    k_linear<<<512, 256, 0, stream>>>(B, W2, A, N);
    k_agg<<<(N + 3) / 4, 256, 0, stream>>>((const float2*)A, (float2*)B, col, rowptr, dinv, b2, N);
    // pool + head
    k_pool<<<G, 128, 0, stream>>>(B, batch, Wf, bf, (float*)d_out, N);
}

// Round 5
// 745.987 us; speedup vs baseline: 1.4962x; 1.4962x over previous
//
#include <hip/hip_runtime.h>
#include <hip/hip_bf16.h>
#include <math.h>

// GCN: h1 = relu(Agg(x@W1) + b1); h2 = relu(Agg(h1@W2) + b2);
// out[g] = mean_pool(h2)[g] @ Wf + bf
// Agg uses symmetric deg^-1/2 norm with self-loops (PyG GCNConv default).
// CSR build once per call; pull-based aggregation (no fp atomics in hot path).
// R4: replaced 64-block serial pool (395us, 1.4% occupancy) with
//     wave-sliced partial sums + atomic flush at graph boundaries.

#define DFEAT 128

__global__ void k_zero2(int* __restrict__ a, int* __restrict__ b, int n) {
    int i = blockIdx.x * blockDim.x + threadIdx.x;
    if (i < n) { a[i] = 0; b[i] = 0; }
}

__global__ void k_zero_f(float* __restrict__ p, int n) {
    int i = blockIdx.x * blockDim.x + threadIdx.x;
    if (i < n) p[i] = 0.f;
}

__global__ void k_degcount(const int* __restrict__ dst, int* __restrict__ degcnt, int E) {
    int e = blockIdx.x * blockDim.x + threadIdx.x;
    if (e < E) atomicAdd(&degcnt[dst[e]], 1);
}

// Single-block exclusive scan of degcnt[0..N) -> rowptr[0..N]
__global__ __launch_bounds__(1024) void k_scan(const int* __restrict__ degcnt,
                                               int* __restrict__ rowptr, int N) {
    __shared__ int lds[1024];
    int tid = threadIdx.x;
    int chunk = (N + 1023) >> 10;
    int beg = tid * chunk;
    int end = min(beg + chunk, N);
    int s = 0;
    for (int i = beg; i < end; ++i) s += degcnt[i];
    lds[tid] = s;
    __syncthreads();
    for (int off = 1; off < 1024; off <<= 1) {
        int v = (tid >= off) ? lds[tid - off] : 0;
        __syncthreads();
        lds[tid] += v;
        __syncthreads();
    }
    int run = (tid == 0) ? 0 : lds[tid - 1];  // exclusive base for this chunk
    for (int i = beg; i < end; ++i) { rowptr[i] = run; run += degcnt[i]; }
    if (beg < N && end == N) rowptr[N] = run;  // == E
}

__global__ void k_dinv(const int* __restrict__ degcnt, float* __restrict__ dinv, int N) {
    int i = blockIdx.x * blockDim.x + threadIdx.x;
    if (i < N) dinv[i] = rsqrtf((float)(degcnt[i] + 1));  // +1 self-loop
}

__global__ void k_fill(const int* __restrict__ src, const int* __restrict__ dst,
                       const int* __restrict__ rowptr, int* __restrict__ fill,
                       int* __restrict__ col, int E) {
    int e = blockIdx.x * blockDim.x + threadIdx.x;
    if (e < E) {
        int d = dst[e];
        int pos = rowptr[d] + atomicAdd(&fill[d], 1);
        col[pos] = src[e];
    }
}

// C[N,128] = H[N,128] @ W[128,128], f32, W staged in LDS.
__global__ __launch_bounds__(256, 2) void k_linear(const float* __restrict__ H,
                                                   const float* __restrict__ W,
                                                   float* __restrict__ C, int N) {
    __shared__ float Wl[128 * 128];   // 64 KB
    __shared__ float inS[32 * 128];   // 16 KB
    int tid = threadIdx.x;
    {
        const float4* W4 = (const float4*)W;
        float4* Wl4 = (float4*)Wl;
#pragma unroll
        for (int j = 0; j < 16; ++j) Wl4[tid + j * 256] = W4[tid + j * 256];
    }
    int cg = tid & 31;
    int r0 = (tid >> 5) * 4;
    int ntiles = (N + 31) >> 5;
    const float4* WL4 = (const float4*)Wl;
    for (int tile = blockIdx.x; tile < ntiles; tile += gridDim.x) {
        int rbase = tile * 32;
        __syncthreads();
        {
            const float4* H4 = (const float4*)(H + (size_t)rbase * DFEAT);
            float4* I4 = (float4*)inS;
            int lim = (N - rbase) * 32;
#pragma unroll
            for (int j = 0; j < 4; ++j) {
                int idx = tid + j * 256;
                float4 v = make_float4(0.f, 0.f, 0.f, 0.f);
                if (idx < lim) v = H4[idx];
                I4[idx] = v;
            }
        }
        __syncthreads();
        float4 a0 = {0,0,0,0}, a1 = {0,0,0,0}, a2 = {0,0,0,0}, a3 = {0,0,0,0};
#pragma unroll 4
        for (int k = 0; k < 128; ++k) {
            float4 w = WL4[k * 32 + cg];
            float x0 = inS[(r0 + 0) * 128 + k];
            float x1 = inS[(r0 + 1) * 128 + k];
            float x2 = inS[(r0 + 2) * 128 + k];
            float x3 = inS[(r0 + 3) * 128 + k];
            a0.x += x0 * w.x; a0.y += x0 * w.y; a0.z += x0 * w.z; a0.w += x0 * w.w;
            a1.x += x1 * w.x; a1.y += x1 * w.y; a1.z += x1 * w.z; a1.w += x1 * w.w;
            a2.x += x2 * w.x; a2.y += x2 * w.y; a2.z += x2 * w.z; a2.w += x2 * w.w;
            a3.x += x3 * w.x; a3.y += x3 * w.y; a3.z += x3 * w.z; a3.w += x3 * w.w;
        }
        int row = rbase + r0;
        if (row + 0 < N) ((float4*)(C + (size_t)(row + 0) * DFEAT))[cg] = a0;
        if (row + 1 < N) ((float4*)(C + (size_t)(row + 1) * DFEAT))[cg] = a1;
        if (row + 2 < N) ((float4*)(C + (size_t)(row + 2) * DFEAT))[cg] = a2;
        if (row + 3 < N) ((float4*)(C + (size_t)(row + 3) * DFEAT))[cg] = a3;
    }
}

// Pull aggregation: one 64-lane wave per node, float2 per lane.
__global__ __launch_bounds__(256) void k_agg(const float2* __restrict__ T2,
                                             float2* __restrict__ Hout,
                                             const int* __restrict__ col,
                                             const int* __restrict__ rowptr,
                                             const float* __restrict__ dinv,
                                             const float* __restrict__ bias, int N) {
    int lane = threadIdx.x & 63;
    int node = blockIdx.x * 4 + (threadIdx.x >> 6);
    if (node >= N) return;
    float2 b = ((const float2*)bias)[lane];
    float di = dinv[node];
    float2 self = T2[(size_t)node * 64 + lane];
    float ws = di * di;
    float2 acc;
    acc.x = self.x * ws;
    acc.y = self.y * ws;
    int beg = rowptr[node], end = rowptr[node + 1];
    if (beg < end) {
        int s_next = col[beg];
        for (int j = beg; j < end; ++j) {
            int s = s_next;
            if (j + 1 < end) s_next = col[j + 1];   // prefetch next col id
            float w = dinv[s] * di;
            float2 v = T2[(size_t)s * 64 + lane];
            acc.x += w * v.x;
            acc.y += w * v.y;
        }
    }
    acc.x = fmaxf(acc.x + b.x, 0.f);
    acc.y = fmaxf(acc.y + b.y, 0.f);
    Hout[(size_t)node * 64 + lane] = acc;
}

// Phase 1 pooling: each wave owns a contiguous node slice (batch sorted),
// accumulates full 128-feat row in registers, flushes to gsum at graph changes.
__global__ __launch_bounds__(256) void k_pool_sum(const float2* __restrict__ Hn,
                                                  const int* __restrict__ batch,
                                                  float* __restrict__ gsum,
                                                  int N, int waves_total) {
    int w = blockIdx.x * 4 + (threadIdx.x >> 6);
    int lane = threadIdx.x & 63;
    int per = (N + waves_total - 1) / waves_total;
    int n0 = w * per;
    int n1 = min(N, n0 + per);
    if (n0 >= n1) return;
    int gcur = batch[n0];
    float2 acc = make_float2(0.f, 0.f);
    for (int i = n0; i < n1; ++i) {
        int g = batch[i];
        if (g != gcur) {
            atomicAdd(&gsum[gcur * DFEAT + lane * 2 + 0], acc.x);
            atomicAdd(&gsum[gcur * DFEAT + lane * 2 + 1], acc.y);
            acc = make_float2(0.f, 0.f);
            gcur = g;
        }
        float2 v = Hn[(size_t)i * 64 + lane];
        acc.x += v.x;
        acc.y += v.y;
    }
    atomicAdd(&gsum[gcur * DFEAT + lane * 2 + 0], acc.x);
    atomicAdd(&gsum[gcur * DFEAT + lane * 2 + 1], acc.y);
}

// Phase 2: divide by count (binary search on sorted batch), dot Wf, +bf.
__global__ __launch_bounds__(128) void k_head(const float* __restrict__ gsum,
                                              const int* __restrict__ batch,
                                              const float* __restrict__ Wf,
                                              const float* __restrict__ bf,
                                              float* __restrict__ out, int N) {
    int g = blockIdx.x;
    int tid = threadIdx.x;
    int l = 0, h = N;
    while (l < h) { int m = (l + h) >> 1; if (batch[m] < g) l = m + 1; else h = m; }
    int lo = l;
    h = N;
    while (l < h) { int m = (l + h) >> 1; if (batch[m] < g + 1) l = m + 1; else h = m; }
    int hi = l;
    float cnt = (float)((hi - lo) > 0 ? (hi - lo) : 1);
    float val = (gsum[g * DFEAT + tid] / cnt) * Wf[tid];
    for (int off = 32; off >= 1; off >>= 1) val += __shfl_down(val, off, 64);
    __shared__ float ws2[2];
    if ((tid & 63) == 0) ws2[tid >> 6] = val;
    __syncthreads();
    if (tid == 0) out[g] = ws2[0] + ws2[1] + bf[0];
}

extern "C" void kernel_launch(void* const* d_in, const int* in_sizes, int n_in,
                              void* d_out, int out_size, void* d_ws, size_t ws_size,
                              hipStream_t stream) {
    const float* x    = (const float*)d_in[0];
    const int*   ei   = (const int*)d_in[1];
    const int*   batch= (const int*)d_in[2];
    const float* W1   = (const float*)d_in[3];
    const float* b1   = (const float*)d_in[4];
    const float* W2   = (const float*)d_in[5];
    const float* b2   = (const float*)d_in[6];
    const float* Wf   = (const float*)d_in[7];
    const float* bf   = (const float*)d_in[8];

    int N = in_sizes[0] / DFEAT;
    int E = in_sizes[1] / 2;
    int G = out_size;  // num_graphs

    const int* src = ei;
    const int* dst = ei + E;

    char* wsb = (char*)d_ws;
    size_t off = 0;
    auto walloc = [&](size_t bytes) {
        void* p = wsb + off;
        off = (off + bytes + 255) & ~(size_t)255;
        return p;
    };
    float* A      = (float*)walloc((size_t)N * DFEAT * sizeof(float)); // 51.2 MB
    float* B      = (float*)walloc((size_t)N * DFEAT * sizeof(float)); // 51.2 MB
    float* dinv   = (float*)walloc((size_t)N * sizeof(float));
    int*   rowptr = (int*)  walloc((size_t)(N + 1) * sizeof(int));
    int*   col    = (int*)  walloc((size_t)E * sizeof(int));           // 6.4 MB
    int*   degcnt = (int*)  walloc((size_t)N * sizeof(int));
    int*   fill   = (int*)  walloc((size_t)N * sizeof(int));
    float* gsum   = (float*)walloc((size_t)G * DFEAT * sizeof(float)); // 32 KB
    (void)ws_size; (void)n_in;

    int gN = (N + 255) / 256;
    int gE = (E + 255) / 256;

    // CSR build
    k_zero2<<<gN, 256, 0, stream>>>(degcnt, fill, N);
    k_zero_f<<<(G * DFEAT + 255) / 256, 256, 0, stream>>>(gsum, G * DFEAT);
    k_degcount<<<gE, 256, 0, stream>>>(dst, degcnt, E);
    k_scan<<<1, 1024, 0, stream>>>(degcnt, rowptr, N);
    k_dinv<<<gN, 256, 0, stream>>>(degcnt, dinv, N);
    k_fill<<<gE, 256, 0, stream>>>(src, dst, rowptr, fill, col, E);

    // layer 1
    k_linear<<<512, 256, 0, stream>>>(x, W1, A, N);
    k_agg<<<(N + 3) / 4, 256, 0, stream>>>((const float2*)A, (float2*)B, col, rowptr, dinv, b1, N);
    // layer 2
    k_linear<<<512, 256, 0, stream>>>(B, W2, A, N);
    k_agg<<<(N + 3) / 4, 256, 0, stream>>>((const float2*)A, (float2*)B, col, rowptr, dinv, b2, N);

    // pool + head
    const int POOL_BLOCKS = 1024;
    k_pool_sum<<<POOL_BLOCKS, 256, 0, stream>>>((const float2*)B, batch, gsum, N, POOL_BLOCKS * 4);
    k_head<<<G, 128, 0, stream>>>(gsum, batch, Wf, bf, (float*)d_out, N);
}

// Round 6
// 597.532 us; speedup vs baseline: 1.8680x; 1.2484x over previous
//
#include <hip/hip_runtime.h>
#include <hip/hip_bf16.h>
#include <math.h>

// GCN: h1 = relu(Agg(x@W1) + b1); h2 = relu(Agg(h1@W2) + b2);
// out[g] = mean_pool(h2)[g] @ Wf + bf
// Agg uses symmetric deg^-1/2 norm with self-loops (PyG GCNConv default).
// CSR build once per call; pull-based aggregation (no fp atomics in hot path).
// R4: wave-sliced pool (k_pool 395us @1.4% occ -> ~15us).
// R5: decoupled 3-phase scan (k_scan 162us @0.16% occ, single block -> ~12us),
//     dinv folded into k_writeptr.

#define DFEAT 128
#define SCAN_NB 256
#define SCAN_TPB 256

__global__ void k_zero2(int* __restrict__ a, int* __restrict__ b, int n) {
    int i = blockIdx.x * blockDim.x + threadIdx.x;
    if (i < n) { a[i] = 0; b[i] = 0; }
}

__global__ void k_zero_f(float* __restrict__ p, int n) {
    int i = blockIdx.x * blockDim.x + threadIdx.x;
    if (i < n) p[i] = 0.f;
}

__global__ void k_degcount(const int* __restrict__ dst, int* __restrict__ degcnt, int E) {
    int e = blockIdx.x * blockDim.x + threadIdx.x;
    if (e < E) atomicAdd(&degcnt[dst[e]], 1);
}

// Scan phase 1: block b owns [b*chunk, min(N,(b+1)*chunk)); coalesced strided
// reads, LDS tree reduce -> bsum[b].
__global__ __launch_bounds__(SCAN_TPB) void k_partsum(const int* __restrict__ deg,
                                                      int* __restrict__ bsum,
                                                      int N, int chunk) {
    int b = blockIdx.x, tid = threadIdx.x;
    int beg = b * chunk, end = min(N, beg + chunk);
    int s = 0;
    for (int i = beg + tid; i < end; i += SCAN_TPB) s += deg[i];
    __shared__ int lds[SCAN_TPB];
    lds[tid] = s;
    __syncthreads();
    for (int off = SCAN_TPB / 2; off > 0; off >>= 1) {
        if (tid < off) lds[tid] += lds[tid + off];
        __syncthreads();
    }
    if (tid == 0) bsum[b] = lds[0];
}

// Scan phase 2: single 256-thread block, exclusive scan of bsum in place.
__global__ __launch_bounds__(SCAN_NB) void k_scanb(int* __restrict__ bsum) {
    __shared__ int lds[SCAN_NB];
    int tid = threadIdx.x;
    int v = bsum[tid];
    lds[tid] = v;
    __syncthreads();
    for (int off = 1; off < SCAN_NB; off <<= 1) {
        int t = (tid >= off) ? lds[tid - off] : 0;
        __syncthreads();
        lds[tid] += t;
        __syncthreads();
    }
    bsum[tid] = lds[tid] - v;  // exclusive base
}

// Scan phase 3: per-thread contiguous sub-chunks, block scan of thread sums,
// write rowptr[i] (+ rowptr[N]=E by the unique thread ending at N).
// Also emits dinv[i] = rsqrt(deg[i]+1) for free.
__global__ __launch_bounds__(SCAN_TPB) void k_writeptr(const int* __restrict__ deg,
                                                       const int* __restrict__ bbase,
                                                       int* __restrict__ rowptr,
                                                       float* __restrict__ dinv,
                                                       int N, int chunk) {
    int b = blockIdx.x, tid = threadIdx.x;
    int beg = b * chunk, end = min(N, beg + chunk);
    int per = (chunk + SCAN_TPB - 1) / SCAN_TPB;
    int tbeg = beg + tid * per;
    int tend = min(end, tbeg + per);
    int s = 0;
    for (int i = tbeg; i < tend; ++i) s += deg[i];
    __shared__ int lds[SCAN_TPB];
    lds[tid] = s;
    __syncthreads();
    for (int off = 1; off < SCAN_TPB; off <<= 1) {
        int t = (tid >= off) ? lds[tid - off] : 0;
        __syncthreads();
        lds[tid] += t;
        __syncthreads();
    }
    int run = bbase[b] + ((tid == 0) ? 0 : lds[tid - 1]);
    for (int i = tbeg; i < tend; ++i) {
        int d = deg[i];
        rowptr[i] = run;
        dinv[i] = rsqrtf((float)(d + 1));  // +1 self-loop
        run += d;
    }
    if (tend == N && tbeg < tend) rowptr[N] = run;  // == E
}

__global__ void k_fill(const int* __restrict__ src, const int* __restrict__ dst,
                       const int* __restrict__ rowptr, int* __restrict__ fill,
                       int* __restrict__ col, int E) {
    int e = blockIdx.x * blockDim.x + threadIdx.x;
    if (e < E) {
        int d = dst[e];
        int pos = rowptr[d] + atomicAdd(&fill[d], 1);
        col[pos] = src[e];
    }
}

// C[N,128] = H[N,128] @ W[128,128], f32, W staged in LDS.
__global__ __launch_bounds__(256, 2) void k_linear(const float* __restrict__ H,
                                                   const float* __restrict__ W,
                                                   float* __restrict__ C, int N) {
    __shared__ float Wl[128 * 128];   // 64 KB
    __shared__ float inS[32 * 128];   // 16 KB
    int tid = threadIdx.x;
    {
        const float4* W4 = (const float4*)W;
        float4* Wl4 = (float4*)Wl;
#pragma unroll
        for (int j = 0; j < 16; ++j) Wl4[tid + j * 256] = W4[tid + j * 256];
    }
    int cg = tid & 31;
    int r0 = (tid >> 5) * 4;
    int ntiles = (N + 31) >> 5;
    const float4* WL4 = (const float4*)Wl;
    for (int tile = blockIdx.x; tile < ntiles; tile += gridDim.x) {
        int rbase = tile * 32;
        __syncthreads();
        {
            const float4* H4 = (const float4*)(H + (size_t)rbase * DFEAT);
            float4* I4 = (float4*)inS;
            int lim = (N - rbase) * 32;
#pragma unroll
            for (int j = 0; j < 4; ++j) {
                int idx = tid + j * 256;
                float4 v = make_float4(0.f, 0.f, 0.f, 0.f);
                if (idx < lim) v = H4[idx];
                I4[idx] = v;
            }
        }
        __syncthreads();
        float4 a0 = {0,0,0,0}, a1 = {0,0,0,0}, a2 = {0,0,0,0}, a3 = {0,0,0,0};
#pragma unroll 4
        for (int k = 0; k < 128; ++k) {
            float4 w = WL4[k * 32 + cg];
            float x0 = inS[(r0 + 0) * 128 + k];
            float x1 = inS[(r0 + 1) * 128 + k];
            float x2 = inS[(r0 + 2) * 128 + k];
            float x3 = inS[(r0 + 3) * 128 + k];
            a0.x += x0 * w.x; a0.y += x0 * w.y; a0.z += x0 * w.z; a0.w += x0 * w.w;
            a1.x += x1 * w.x; a1.y += x1 * w.y; a1.z += x1 * w.z; a1.w += x1 * w.w;
            a2.x += x2 * w.x; a2.y += x2 * w.y; a2.z += x2 * w.z; a2.w += x2 * w.w;
            a3.x += x3 * w.x; a3.y += x3 * w.y; a3.z += x3 * w.z; a3.w += x3 * w.w;
        }
        int row = rbase + r0;
        if (row + 0 < N) ((float4*)(C + (size_t)(row + 0) * DFEAT))[cg] = a0;
        if (row + 1 < N) ((float4*)(C + (size_t)(row + 1) * DFEAT))[cg] = a1;
        if (row + 2 < N) ((float4*)(C + (size_t)(row + 2) * DFEAT))[cg] = a2;
        if (row + 3 < N) ((float4*)(C + (size_t)(row + 3) * DFEAT))[cg] = a3;
    }
}

// Pull aggregation: one 64-lane wave per node, float2 per lane.
__global__ __launch_bounds__(256) void k_agg(const float2* __restrict__ T2,
                                             float2* __restrict__ Hout,
                                             const int* __restrict__ col,
                                             const int* __restrict__ rowptr,
                                             const float* __restrict__ dinv,
                                             const float* __restrict__ bias, int N) {
    int lane = threadIdx.x & 63;
    int node = blockIdx.x * 4 + (threadIdx.x >> 6);
    if (node >= N) return;
    float2 b = ((const float2*)bias)[lane];
    float di = dinv[node];
    float2 self = T2[(size_t)node * 64 + lane];
    float ws = di * di;
    float2 acc;
    acc.x = self.x * ws;
    acc.y = self.y * ws;
    int beg = rowptr[node], end = rowptr[node + 1];
    if (beg < end) {
        int s_next = col[beg];
        for (int j = beg; j < end; ++j) {
            int s = s_next;
            if (j + 1 < end) s_next = col[j + 1];   // prefetch next col id
            float w = dinv[s] * di;
            float2 v = T2[(size_t)s * 64 + lane];
            acc.x += w * v.x;
            acc.y += w * v.y;
        }
    }
    acc.x = fmaxf(acc.x + b.x, 0.f);
    acc.y = fmaxf(acc.y + b.y, 0.f);
    Hout[(size_t)node * 64 + lane] = acc;
}

// Pool phase 1: each wave owns a contiguous node slice (batch sorted),
// register accumulation, atomic flush at graph boundaries.
__global__ __launch_bounds__(256) void k_pool_sum(const float2* __restrict__ Hn,
                                                  const int* __restrict__ batch,
                                                  float* __restrict__ gsum,
                                                  int N, int waves_total) {
    int w = blockIdx.x * 4 + (threadIdx.x >> 6);
    int lane = threadIdx.x & 63;
    int per = (N + waves_total - 1) / waves_total;
    int n0 = w * per;
    int n1 = min(N, n0 + per);
    if (n0 >= n1) return;
    int gcur = batch[n0];
    float2 acc = make_float2(0.f, 0.f);
    for (int i = n0; i < n1; ++i) {
        int g = batch[i];
        if (g != gcur) {
            atomicAdd(&gsum[gcur * DFEAT + lane * 2 + 0], acc.x);
            atomicAdd(&gsum[gcur * DFEAT + lane * 2 + 1], acc.y);
            acc = make_float2(0.f, 0.f);
            gcur = g;
        }
        float2 v = Hn[(size_t)i * 64 + lane];
        acc.x += v.x;
        acc.y += v.y;
    }
    atomicAdd(&gsum[gcur * DFEAT + lane * 2 + 0], acc.x);
    atomicAdd(&gsum[gcur * DFEAT + lane * 2 + 1], acc.y);
}

// Pool phase 2: divide by count (binary search on sorted batch), dot Wf, +bf.
__global__ __launch_bounds__(128) void k_head(const float* __restrict__ gsum,
                                              const int* __restrict__ batch,
                                              const float* __restrict__ Wf,
                                              const float* __restrict__ bf,
                                              float* __restrict__ out, int N) {
    int g = blockIdx.x;
    int tid = threadIdx.x;
    int l = 0, h = N;
    while (l < h) { int m = (l + h) >> 1; if (batch[m] < g) l = m + 1; else h = m; }
    int lo = l;
    h = N;
    while (l < h) { int m = (l + h) >> 1; if (batch[m] < g + 1) l = m + 1; else h = m; }
    int hi = l;
    float cnt = (float)((hi - lo) > 0 ? (hi - lo) : 1);
    float val = (gsum[g * DFEAT + tid] / cnt) * Wf[tid];
    for (int off = 32; off >= 1; off >>= 1) val += __shfl_down(val, off, 64);
    __shared__ float ws2[2];
    if ((tid & 63) == 0) ws2[tid >> 6] = val;
    __syncthreads();
    if (tid == 0) out[g] = ws2[0] + ws2[1] + bf[0];
}

extern "C" void kernel_launch(void* const* d_in, const int* in_sizes, int n_in,
                              void* d_out, int out_size, void* d_ws, size_t ws_size,
                              hipStream_t stream) {
    const float* x    = (const float*)d_in[0];
    const int*   ei   = (const int*)d_in[1];
    const int*   batch= (const int*)d_in[2];
    const float* W1   = (const float*)d_in[3];
    const float* b1   = (const float*)d_in[4];
    const float* W2   = (const float*)d_in[5];
    const float* b2   = (const float*)d_in[6];
    const float* Wf   = (const float*)d_in[7];
    const float* bf   = (const float*)d_in[8];

    int N = in_sizes[0] / DFEAT;
    int E = in_sizes[1] / 2;
    int G = out_size;  // num_graphs

    const int* src = ei;
    const int* dst = ei + E;

    char* wsb = (char*)d_ws;
    size_t off = 0;
    auto walloc = [&](size_t bytes) {
        void* p = wsb + off;
        off = (off + bytes + 255) & ~(size_t)255;
        return p;
    };
    float* A      = (float*)walloc((size_t)N * DFEAT * sizeof(float)); // 51.2 MB
    float* B      = (float*)walloc((size_t)N * DFEAT * sizeof(float)); // 51.2 MB
    float* dinv   = (float*)walloc((size_t)N * sizeof(float));
    int*   rowptr = (int*)  walloc((size_t)(N + 1) * sizeof(int));
    int*   col    = (int*)  walloc((size_t)E * sizeof(int));           // 6.4 MB
    int*   degcnt = (int*)  walloc((size_t)N * sizeof(int));
    int*   fill   = (int*)  walloc((size_t)N * sizeof(int));
    float* gsum   = (float*)walloc((size_t)G * DFEAT * sizeof(float)); // 32 KB
    int*   bsum   = (int*)  walloc((size_t)SCAN_NB * sizeof(int));
    (void)ws_size; (void)n_in;

    int gN = (N + 255) / 256;
    int gE = (E + 255) / 256;
    int chunk = (N + SCAN_NB - 1) / SCAN_NB;

    // CSR build
    k_zero2<<<gN, 256, 0, stream>>>(degcnt, fill, N);
    k_zero_f<<<(G * DFEAT + 255) / 256, 256, 0, stream>>>(gsum, G * DFEAT);
    k_degcount<<<gE, 256, 0, stream>>>(dst, degcnt, E);
    k_partsum<<<SCAN_NB, SCAN_TPB, 0, stream>>>(degcnt, bsum, N, chunk);
    k_scanb<<<1, SCAN_NB, 0, stream>>>(bsum);
    k_writeptr<<<SCAN_NB, SCAN_TPB, 0, stream>>>(degcnt, bsum, rowptr, dinv, N, chunk);
    k_fill<<<gE, 256, 0, stream>>>(src, dst, rowptr, fill, col, E);

    // layer 1
    k_linear<<<512, 256, 0, stream>>>(x, W1, A, N);
    k_agg<<<(N + 3) / 4, 256, 0, stream>>>((const float2*)A, (float2*)B, col, rowptr, dinv, b1, N);
    // layer 2
    k_linear<<<512, 256, 0, stream>>>(B, W2, A, N);
    k_agg<<<(N + 3) / 4, 256, 0, stream>>>((const float2*)A, (float2*)B, col, rowptr, dinv, b2, N);

    // pool + head
    const int POOL_BLOCKS = 1024;
    k_pool_sum<<<POOL_BLOCKS, 256, 0, stream>>>((const float2*)B, batch, gsum, N, POOL_BLOCKS * 4);
    k_head<<<G, 128, 0, stream>>>(gsum, batch, Wf, bf, (float*)d_out, N);
}

// Round 7
// 573.263 us; speedup vs baseline: 1.9470x; 1.0423x over previous
//
#include <hip/hip_runtime.h>
#include <hip/hip_bf16.h>
#include <math.h>

// GCN: h1 = relu(Agg(x@W1) + b1); h2 = relu(Agg(h1@W2) + b2);
// out[g] = mean_pool(h2)[g] @ Wf + bf
// Agg uses symmetric deg^-1/2 norm with self-loops (PyG GCNConv default).
// CSR build once per call; pull-based aggregation (no fp atomics in hot path).
// R4: wave-sliced pool (k_pool 395us @1.4% occ -> ~15us).
// R5: decoupled 3-phase scan (k_scan 162us -> ~12us), dinv folded in.
// R6: k_agg neighbor loop unrolled x4 (1 -> 4 outstanding 512B gathers/wave;
//     was latency-bound at 3.6TB/s, VALUBusy 26%, occ 74%).

#define DFEAT 128
#define SCAN_NB 256
#define SCAN_TPB 256

__global__ void k_zero2(int* __restrict__ a, int* __restrict__ b, int n) {
    int i = blockIdx.x * blockDim.x + threadIdx.x;
    if (i < n) { a[i] = 0; b[i] = 0; }
}

__global__ void k_zero_f(float* __restrict__ p, int n) {
    int i = blockIdx.x * blockDim.x + threadIdx.x;
    if (i < n) p[i] = 0.f;
}

__global__ void k_degcount(const int* __restrict__ dst, int* __restrict__ degcnt, int E) {
    int e = blockIdx.x * blockDim.x + threadIdx.x;
    if (e < E) atomicAdd(&degcnt[dst[e]], 1);
}

// Scan phase 1: block b owns [b*chunk, ...); coalesced reads, LDS tree reduce.
__global__ __launch_bounds__(SCAN_TPB) void k_partsum(const int* __restrict__ deg,
                                                      int* __restrict__ bsum,
                                                      int N, int chunk) {
    int b = blockIdx.x, tid = threadIdx.x;
    int beg = b * chunk, end = min(N, beg + chunk);
    int s = 0;
    for (int i = beg + tid; i < end; i += SCAN_TPB) s += deg[i];
    __shared__ int lds[SCAN_TPB];
    lds[tid] = s;
    __syncthreads();
    for (int off = SCAN_TPB / 2; off > 0; off >>= 1) {
        if (tid < off) lds[tid] += lds[tid + off];
        __syncthreads();
    }
    if (tid == 0) bsum[b] = lds[0];
}

// Scan phase 2: single 256-thread block, exclusive scan of bsum in place.
__global__ __launch_bounds__(SCAN_NB) void k_scanb(int* __restrict__ bsum) {
    __shared__ int lds[SCAN_NB];
    int tid = threadIdx.x;
    int v = bsum[tid];
    lds[tid] = v;
    __syncthreads();
    for (int off = 1; off < SCAN_NB; off <<= 1) {
        int t = (tid >= off) ? lds[tid - off] : 0;
        __syncthreads();
        lds[tid] += t;
        __syncthreads();
    }
    bsum[tid] = lds[tid] - v;  // exclusive base
}

// Scan phase 3: per-thread sub-chunks, block scan, write rowptr (+dinv).
__global__ __launch_bounds__(SCAN_TPB) void k_writeptr(const int* __restrict__ deg,
                                                       const int* __restrict__ bbase,
                                                       int* __restrict__ rowptr,
                                                       float* __restrict__ dinv,
                                                       int N, int chunk) {
    int b = blockIdx.x, tid = threadIdx.x;
    int beg = b * chunk, end = min(N, beg + chunk);
    int per = (chunk + SCAN_TPB - 1) / SCAN_TPB;
    int tbeg = beg + tid * per;
    int tend = min(end, tbeg + per);
    int s = 0;
    for (int i = tbeg; i < tend; ++i) s += deg[i];
    __shared__ int lds[SCAN_TPB];
    lds[tid] = s;
    __syncthreads();
    for (int off = 1; off < SCAN_TPB; off <<= 1) {
        int t = (tid >= off) ? lds[tid - off] : 0;
        __syncthreads();
        lds[tid] += t;
        __syncthreads();
    }
    int run = bbase[b] + ((tid == 0) ? 0 : lds[tid - 1]);
    for (int i = tbeg; i < tend; ++i) {
        int d = deg[i];
        rowptr[i] = run;
        dinv[i] = rsqrtf((float)(d + 1));  // +1 self-loop
        run += d;
    }
    if (tend == N && tbeg < tend) rowptr[N] = run;  // == E
}

__global__ void k_fill(const int* __restrict__ src, const int* __restrict__ dst,
                       const int* __restrict__ rowptr, int* __restrict__ fill,
                       int* __restrict__ col, int E) {
    int e = blockIdx.x * blockDim.x + threadIdx.x;
    if (e < E) {
        int d = dst[e];
        int pos = rowptr[d] + atomicAdd(&fill[d], 1);
        col[pos] = src[e];
    }
}

// C[N,128] = H[N,128] @ W[128,128], f32, W staged in LDS.
__global__ __launch_bounds__(256, 2) void k_linear(const float* __restrict__ H,
                                                   const float* __restrict__ W,
                                                   float* __restrict__ C, int N) {
    __shared__ float Wl[128 * 128];   // 64 KB
    __shared__ float inS[32 * 128];   // 16 KB
    int tid = threadIdx.x;
    {
        const float4* W4 = (const float4*)W;
        float4* Wl4 = (float4*)Wl;
#pragma unroll
        for (int j = 0; j < 16; ++j) Wl4[tid + j * 256] = W4[tid + j * 256];
    }
    int cg = tid & 31;
    int r0 = (tid >> 5) * 4;
    int ntiles = (N + 31) >> 5;
    const float4* WL4 = (const float4*)Wl;
    for (int tile = blockIdx.x; tile < ntiles; tile += gridDim.x) {
        int rbase = tile * 32;
        __syncthreads();
        {
            const float4* H4 = (const float4*)(H + (size_t)rbase * DFEAT);
            float4* I4 = (float4*)inS;
            int lim = (N - rbase) * 32;
#pragma unroll
            for (int j = 0; j < 4; ++j) {
                int idx = tid + j * 256;
                float4 v = make_float4(0.f, 0.f, 0.f, 0.f);
                if (idx < lim) v = H4[idx];
                I4[idx] = v;
            }
        }
        __syncthreads();
        float4 a0 = {0,0,0,0}, a1 = {0,0,0,0}, a2 = {0,0,0,0}, a3 = {0,0,0,0};
#pragma unroll 4
        for (int k = 0; k < 128; ++k) {
            float4 w = WL4[k * 32 + cg];
            float x0 = inS[(r0 + 0) * 128 + k];
            float x1 = inS[(r0 + 1) * 128 + k];
            float x2 = inS[(r0 + 2) * 128 + k];
            float x3 = inS[(r0 + 3) * 128 + k];
            a0.x += x0 * w.x; a0.y += x0 * w.y; a0.z += x0 * w.z; a0.w += x0 * w.w;
            a1.x += x1 * w.x; a1.y += x1 * w.y; a1.z += x1 * w.z; a1.w += x1 * w.w;
            a2.x += x2 * w.x; a2.y += x2 * w.y; a2.z += x2 * w.z; a2.w += x2 * w.w;
            a3.x += x3 * w.x; a3.y += x3 * w.y; a3.z += x3 * w.z; a3.w += x3 * w.w;
        }
        int row = rbase + r0;
        if (row + 0 < N) ((float4*)(C + (size_t)(row + 0) * DFEAT))[cg] = a0;
        if (row + 1 < N) ((float4*)(C + (size_t)(row + 1) * DFEAT))[cg] = a1;
        if (row + 2 < N) ((float4*)(C + (size_t)(row + 2) * DFEAT))[cg] = a2;
        if (row + 3 < N) ((float4*)(C + (size_t)(row + 3) * DFEAT))[cg] = a3;
    }
}

// Pull aggregation: one 64-lane wave per node, float2 per lane.
// R6: 4x unroll -> 4 independent gathers in flight per wave (MLP).
__global__ __launch_bounds__(256) void k_agg(const float2* __restrict__ T2,
                                             float2* __restrict__ Hout,
                                             const int* __restrict__ col,
                                             const int* __restrict__ rowptr,
                                             const float* __restrict__ dinv,
                                             const float* __restrict__ bias, int N) {
    int lane = threadIdx.x & 63;
    int node = blockIdx.x * 4 + (threadIdx.x >> 6);
    if (node >= N) return;
    float2 b = ((const float2*)bias)[lane];
    float di = dinv[node];
    float2 self = T2[(size_t)node * 64 + lane];
    float ws = di * di;
    float2 acc;
    acc.x = self.x * ws;
    acc.y = self.y * ws;
    int beg = rowptr[node], end = rowptr[node + 1];
    int j = beg;
    for (; j + 3 < end; j += 4) {
        int s0 = col[j + 0];
        int s1 = col[j + 1];
        int s2 = col[j + 2];
        int s3 = col[j + 3];
        float w0 = dinv[s0] * di;
        float w1 = dinv[s1] * di;
        float w2 = dinv[s2] * di;
        float w3 = dinv[s3] * di;
        float2 v0 = T2[(size_t)s0 * 64 + lane];
        float2 v1 = T2[(size_t)s1 * 64 + lane];
        float2 v2 = T2[(size_t)s2 * 64 + lane];
        float2 v3 = T2[(size_t)s3 * 64 + lane];
        acc.x += w0 * v0.x; acc.y += w0 * v0.y;
        acc.x += w1 * v1.x; acc.y += w1 * v1.y;
        acc.x += w2 * v2.x; acc.y += w2 * v2.y;
        acc.x += w3 * v3.x; acc.y += w3 * v3.y;
    }
    for (; j < end; ++j) {
        int s = col[j];
        float w = dinv[s] * di;
        float2 v = T2[(size_t)s * 64 + lane];
        acc.x += w * v.x;
        acc.y += w * v.y;
    }
    acc.x = fmaxf(acc.x + b.x, 0.f);
    acc.y = fmaxf(acc.y + b.y, 0.f);
    Hout[(size_t)node * 64 + lane] = acc;
}

// Pool phase 1: wave-sliced partial sums, atomic flush at graph boundaries.
__global__ __launch_bounds__(256) void k_pool_sum(const float2* __restrict__ Hn,
                                                  const int* __restrict__ batch,
                                                  float* __restrict__ gsum,
                                                  int N, int waves_total) {
    int w = blockIdx.x * 4 + (threadIdx.x >> 6);
    int lane = threadIdx.x & 63;
    int per = (N + waves_total - 1) / waves_total;
    int n0 = w * per;
    int n1 = min(N, n0 + per);
    if (n0 >= n1) return;
    int gcur = batch[n0];
    float2 acc = make_float2(0.f, 0.f);
    for (int i = n0; i < n1; ++i) {
        int g = batch[i];
        if (g != gcur) {
            atomicAdd(&gsum[gcur * DFEAT + lane * 2 + 0], acc.x);
            atomicAdd(&gsum[gcur * DFEAT + lane * 2 + 1], acc.y);
            acc = make_float2(0.f, 0.f);
            gcur = g;
        }
        float2 v = Hn[(size_t)i * 64 + lane];
        acc.x += v.x;
        acc.y += v.y;
    }
    atomicAdd(&gsum[gcur * DFEAT + lane * 2 + 0], acc.x);
    atomicAdd(&gsum[gcur * DFEAT + lane * 2 + 1], acc.y);
}

// Pool phase 2: divide by count (binary search on sorted batch), dot Wf, +bf.
__global__ __launch_bounds__(128) void k_head(const float* __restrict__ gsum,
                                              const int* __restrict__ batch,
                                              const float* __restrict__ Wf,
                                              const float* __restrict__ bf,
                                              float* __restrict__ out, int N) {
    int g = blockIdx.x;
    int tid = threadIdx.x;
    int l = 0, h = N;
    while (l < h) { int m = (l + h) >> 1; if (batch[m] < g) l = m + 1; else h = m; }
    int lo = l;
    h = N;
    while (l < h) { int m = (l + h) >> 1; if (batch[m] < g + 1) l = m + 1; else h = m; }
    int hi = l;
    float cnt = (float)((hi - lo) > 0 ? (hi - lo) : 1);
    float val = (gsum[g * DFEAT + tid] / cnt) * Wf[tid];
    for (int off = 32; off >= 1; off >>= 1) val += __shfl_down(val, off, 64);
    __shared__ float ws2[2];
    if ((tid & 63) == 0) ws2[tid >> 6] = val;
    __syncthreads();
    if (tid == 0) out[g] = ws2[0] + ws2[1] + bf[0];
}

extern "C" void kernel_launch(void* const* d_in, const int* in_sizes, int n_in,
                              void* d_out, int out_size, void* d_ws, size_t ws_size,
                              hipStream_t stream) {
    const float* x    = (const float*)d_in[0];
    const int*   ei   = (const int*)d_in[1];
    const int*   batch= (const int*)d_in[2];
    const float* W1   = (const float*)d_in[3];
    const float* b1   = (const float*)d_in[4];
    const float* W2   = (const float*)d_in[5];
    const float* b2   = (const float*)d_in[6];
    const float* Wf   = (const float*)d_in[7];
    const float* bf   = (const float*)d_in[8];

    int N = in_sizes[0] / DFEAT;
    int E = in_sizes[1] / 2;
    int G = out_size;  // num_graphs

    const int* src = ei;
    const int* dst = ei + E;

    char* wsb = (char*)d_ws;
    size_t off = 0;
    auto walloc = [&](size_t bytes) {
        void* p = wsb + off;
        off = (off + bytes + 255) & ~(size_t)255;
        return p;
    };
    float* A      = (float*)walloc((size_t)N * DFEAT * sizeof(float)); // 51.2 MB
    float* B      = (float*)walloc((size_t)N * DFEAT * sizeof(float)); // 51.2 MB
    float* dinv   = (float*)walloc((size_t)N * sizeof(float));
    int*   rowptr = (int*)  walloc((size_t)(N + 1) * sizeof(int));
    int*   col    = (int*)  walloc((size_t)E * sizeof(int));           // 6.4 MB
    int*   degcnt = (int*)  walloc((size_t)N * sizeof(int));
    int*   fill   = (int*)  walloc((size_t)N * sizeof(int));
    float* gsum   = (float*)walloc((size_t)G * DFEAT * sizeof(float)); // 32 KB
    int*   bsum   = (int*)  walloc((size_t)SCAN_NB * sizeof(int));
    (void)ws_size; (void)n_in;

    int gN = (N + 255) / 256;
    int gE = (E + 255) / 256;
    int chunk = (N + SCAN_NB - 1) / SCAN_NB;

    // CSR build
    k_zero2<<<gN, 256, 0, stream>>>(degcnt, fill, N);
    k_zero_f<<<(G * DFEAT + 255) / 256, 256, 0, stream>>>(gsum, G * DFEAT);
    k_degcount<<<gE, 256, 0, stream>>>(dst, degcnt, E);
    k_partsum<<<SCAN_NB, SCAN_TPB, 0, stream>>>(degcnt, bsum, N, chunk);
    k_scanb<<<1, SCAN_NB, 0, stream>>>(bsum);
    k_writeptr<<<SCAN_NB, SCAN_TPB, 0, stream>>>(degcnt, bsum, rowptr, dinv, N, chunk);
    k_fill<<<gE, 256, 0, stream>>>(src, dst, rowptr, fill, col, E);

    // layer 1
    k_linear<<<512, 256, 0, stream>>>(x, W1, A, N);
    k_agg<<<(N + 3) / 4, 256, 0, stream>>>((const float2*)A, (float2*)B, col, rowptr, dinv, b1, N);
    // layer 2
    k_linear<<<512, 256, 0, stream>>>(B, W2, A, N);
    k_agg<<<(N + 3) / 4, 256, 0, stream>>>((const float2*)A, (float2*)B, col, rowptr, dinv, b2, N);

    // pool + head
    const int POOL_BLOCKS = 1024;
    k_pool_sum<<<POOL_BLOCKS, 256, 0, stream>>>((const float2*)B, batch, gsum, N, POOL_BLOCKS * 4);
    k_head<<<G, 128, 0, stream>>>(gsum, batch, Wf, bf, (float*)d_out, N);
}

// Round 8
// 499.513 us; speedup vs baseline: 2.2345x; 1.1476x over previous
//
#include <hip/hip_runtime.h>
#include <hip/hip_bf16.h>
#include <math.h>

// GCN: h1 = relu(Agg(x@W1) + b1); h2 = relu(Agg(h1@W2) + b2);
// out[g] = mean_pool(h2)[g] @ Wf + bf
// Agg: symmetric deg^-1/2 norm with self-loops (PyG GCNConv default).
// CSR build once per call; pull-based aggregation (no fp atomics in hot path).
// R4: wave-sliced pool (395us -> ~15us). R5: decoupled scan (162us -> ~12us).
// R6: k_agg unroll x4 (132 -> 122us; hit ~3.9TB/s gather-BW wall, FETCH 415MB).
// R7: bf16 feature table at linear->agg boundary: halves gather+write bytes.
//     Agg math/output stay f32; only pre-agg activations quantized (RNE).

#define DFEAT 128
#define SCAN_NB 256
#define SCAN_TPB 256

typedef unsigned int uint32;

__device__ __forceinline__ uint32 f2bf_rne(float f) {
    uint32 x = __float_as_uint(f);
    return (x + 0x7fffu + ((x >> 16) & 1u)) >> 16;
}
__device__ __forceinline__ uint32 packbf2(float lo, float hi) {
    return f2bf_rne(lo) | (f2bf_rne(hi) << 16);
}

__global__ void k_zero2(int* __restrict__ a, int* __restrict__ b, int n) {
    int i = blockIdx.x * blockDim.x + threadIdx.x;
    if (i < n) { a[i] = 0; b[i] = 0; }
}

__global__ void k_zero_f(float* __restrict__ p, int n) {
    int i = blockIdx.x * blockDim.x + threadIdx.x;
    if (i < n) p[i] = 0.f;
}

__global__ void k_degcount(const int* __restrict__ dst, int* __restrict__ degcnt, int E) {
    int e = blockIdx.x * blockDim.x + threadIdx.x;
    if (e < E) atomicAdd(&degcnt[dst[e]], 1);
}

// Scan phase 1: block b owns [b*chunk, ...); coalesced reads, LDS tree reduce.
__global__ __launch_bounds__(SCAN_TPB) void k_partsum(const int* __restrict__ deg,
                                                      int* __restrict__ bsum,
                                                      int N, int chunk) {
    int b = blockIdx.x, tid = threadIdx.x;
    int beg = b * chunk, end = min(N, beg + chunk);
    int s = 0;
    for (int i = beg + tid; i < end; i += SCAN_TPB) s += deg[i];
    __shared__ int lds[SCAN_TPB];
    lds[tid] = s;
    __syncthreads();
    for (int off = SCAN_TPB / 2; off > 0; off >>= 1) {
        if (tid < off) lds[tid] += lds[tid + off];
        __syncthreads();
    }
    if (tid == 0) bsum[b] = lds[0];
}

// Scan phase 2: single 256-thread block, exclusive scan of bsum in place.
__global__ __launch_bounds__(SCAN_NB) void k_scanb(int* __restrict__ bsum) {
    __shared__ int lds[SCAN_NB];
    int tid = threadIdx.x;
    int v = bsum[tid];
    lds[tid] = v;
    __syncthreads();
    for (int off = 1; off < SCAN_NB; off <<= 1) {
        int t = (tid >= off) ? lds[tid - off] : 0;
        __syncthreads();
        lds[tid] += t;
        __syncthreads();
    }
    bsum[tid] = lds[tid] - v;  // exclusive base
}

// Scan phase 3: per-thread sub-chunks, block scan, write rowptr (+dinv).
__global__ __launch_bounds__(SCAN_TPB) void k_writeptr(const int* __restrict__ deg,
                                                       const int* __restrict__ bbase,
                                                       int* __restrict__ rowptr,
                                                       float* __restrict__ dinv,
                                                       int N, int chunk) {
    int b = blockIdx.x, tid = threadIdx.x;
    int beg = b * chunk, end = min(N, beg + chunk);
    int per = (chunk + SCAN_TPB - 1) / SCAN_TPB;
    int tbeg = beg + tid * per;
    int tend = min(end, tbeg + per);
    int s = 0;
    for (int i = tbeg; i < tend; ++i) s += deg[i];
    __shared__ int lds[SCAN_TPB];
    lds[tid] = s;
    __syncthreads();
    for (int off = 1; off < SCAN_TPB; off <<= 1) {
        int t = (tid >= off) ? lds[tid - off] : 0;
        __syncthreads();
        lds[tid] += t;
        __syncthreads();
    }
    int run = bbase[b] + ((tid == 0) ? 0 : lds[tid - 1]);
    for (int i = tbeg; i < tend; ++i) {
        int d = deg[i];
        rowptr[i] = run;
        dinv[i] = rsqrtf((float)(d + 1));  // +1 self-loop
        run += d;
    }
    if (tend == N && tbeg < tend) rowptr[N] = run;  // == E
}

__global__ void k_fill(const int* __restrict__ src, const int* __restrict__ dst,
                       const int* __restrict__ rowptr, int* __restrict__ fill,
                       int* __restrict__ col, int E) {
    int e = blockIdx.x * blockDim.x + threadIdx.x;
    if (e < E) {
        int d = dst[e];
        int pos = rowptr[d] + atomicAdd(&fill[d], 1);
        col[pos] = src[e];
    }
}

// C[N,128] (bf16-packed) = H[N,128](f32) @ W[128,128](f32); W staged in LDS.
// Math in f32; output quantized RNE to bf16 (2 features per uint).
__global__ __launch_bounds__(256, 2) void k_linear(const float* __restrict__ H,
                                                   const float* __restrict__ W,
                                                   uint32* __restrict__ C, int N) {
    __shared__ float Wl[128 * 128];   // 64 KB
    __shared__ float inS[32 * 128];   // 16 KB
    int tid = threadIdx.x;
    {
        const float4* W4 = (const float4*)W;
        float4* Wl4 = (float4*)Wl;
#pragma unroll
        for (int j = 0; j < 16; ++j) Wl4[tid + j * 256] = W4[tid + j * 256];
    }
    int cg = tid & 31;
    int r0 = (tid >> 5) * 4;
    int ntiles = (N + 31) >> 5;
    const float4* WL4 = (const float4*)Wl;
    for (int tile = blockIdx.x; tile < ntiles; tile += gridDim.x) {
        int rbase = tile * 32;
        __syncthreads();
        {
            const float4* H4 = (const float4*)(H + (size_t)rbase * DFEAT);
            float4* I4 = (float4*)inS;
            int lim = (N - rbase) * 32;
#pragma unroll
            for (int j = 0; j < 4; ++j) {
                int idx = tid + j * 256;
                float4 v = make_float4(0.f, 0.f, 0.f, 0.f);
                if (idx < lim) v = H4[idx];
                I4[idx] = v;
            }
        }
        __syncthreads();
        float4 a0 = {0,0,0,0}, a1 = {0,0,0,0}, a2 = {0,0,0,0}, a3 = {0,0,0,0};
#pragma unroll 4
        for (int k = 0; k < 128; ++k) {
            float4 w = WL4[k * 32 + cg];
            float x0 = inS[(r0 + 0) * 128 + k];
            float x1 = inS[(r0 + 1) * 128 + k];
            float x2 = inS[(r0 + 2) * 128 + k];
            float x3 = inS[(r0 + 3) * 128 + k];
            a0.x += x0 * w.x; a0.y += x0 * w.y; a0.z += x0 * w.z; a0.w += x0 * w.w;
            a1.x += x1 * w.x; a1.y += x1 * w.y; a1.z += x1 * w.z; a1.w += x1 * w.w;
            a2.x += x2 * w.x; a2.y += x2 * w.y; a2.z += x2 * w.z; a2.w += x2 * w.w;
            a3.x += x3 * w.x; a3.y += x3 * w.y; a3.z += x3 * w.z; a3.w += x3 * w.w;
        }
        int row = rbase + r0;
        // row stride = 64 uints (128 bf16); thread writes uint2 at index cg.
        if (row + 0 < N) ((uint2*)(C + (size_t)(row + 0) * 64))[cg] = make_uint2(packbf2(a0.x, a0.y), packbf2(a0.z, a0.w));
        if (row + 1 < N) ((uint2*)(C + (size_t)(row + 1) * 64))[cg] = make_uint2(packbf2(a1.x, a1.y), packbf2(a1.z, a1.w));
        if (row + 2 < N) ((uint2*)(C + (size_t)(row + 2) * 64))[cg] = make_uint2(packbf2(a2.x, a2.y), packbf2(a2.z, a2.w));
        if (row + 3 < N) ((uint2*)(C + (size_t)(row + 3) * 64))[cg] = make_uint2(packbf2(a3.x, a3.y), packbf2(a3.z, a3.w));
    }
}

// Pull aggregation: one 64-lane wave per node; lane holds features 2*lane,2*lane+1.
// Gathers bf16-packed rows (256B/row), accumulates f32, writes f32.
__global__ __launch_bounds__(256) void k_agg(const uint32* __restrict__ Tb,
                                             float2* __restrict__ Hout,
                                             const int* __restrict__ col,
                                             const int* __restrict__ rowptr,
                                             const float* __restrict__ dinv,
                                             const float* __restrict__ bias, int N) {
    int lane = threadIdx.x & 63;
    int node = blockIdx.x * 4 + (threadIdx.x >> 6);
    if (node >= N) return;
    float2 b = ((const float2*)bias)[lane];
    float di = dinv[node];
    uint32 us = Tb[(size_t)node * 64 + lane];
    float ws = di * di;
    float2 acc;
    acc.x = __uint_as_float(us << 16) * ws;
    acc.y = __uint_as_float(us & 0xffff0000u) * ws;
    int beg = rowptr[node], end = rowptr[node + 1];
    int j = beg;
    for (; j + 3 < end; j += 4) {
        int s0 = col[j + 0];
        int s1 = col[j + 1];
        int s2 = col[j + 2];
        int s3 = col[j + 3];
        float w0 = dinv[s0] * di;
        float w1 = dinv[s1] * di;
        float w2 = dinv[s2] * di;
        float w3 = dinv[s3] * di;
        uint32 u0 = Tb[(size_t)s0 * 64 + lane];
        uint32 u1 = Tb[(size_t)s1 * 64 + lane];
        uint32 u2 = Tb[(size_t)s2 * 64 + lane];
        uint32 u3 = Tb[(size_t)s3 * 64 + lane];
        acc.x += w0 * __uint_as_float(u0 << 16);
        acc.y += w0 * __uint_as_float(u0 & 0xffff0000u);
        acc.x += w1 * __uint_as_float(u1 << 16);
        acc.y += w1 * __uint_as_float(u1 & 0xffff0000u);
        acc.x += w2 * __uint_as_float(u2 << 16);
        acc.y += w2 * __uint_as_float(u2 & 0xffff0000u);
        acc.x += w3 * __uint_as_float(u3 << 16);
        acc.y += w3 * __uint_as_float(u3 & 0xffff0000u);
    }
    for (; j < end; ++j) {
        int s = col[j];
        float w = dinv[s] * di;
        uint32 u = Tb[(size_t)s * 64 + lane];
        acc.x += w * __uint_as_float(u << 16);
        acc.y += w * __uint_as_float(u & 0xffff0000u);
    }
    acc.x = fmaxf(acc.x + b.x, 0.f);
    acc.y = fmaxf(acc.y + b.y, 0.f);
    Hout[(size_t)node * 64 + lane] = acc;
}

// Pool phase 1: wave-sliced partial sums, atomic flush at graph boundaries.
__global__ __launch_bounds__(256) void k_pool_sum(const float2* __restrict__ Hn,
                                                  const int* __restrict__ batch,
                                                  float* __restrict__ gsum,
                                                  int N, int waves_total) {
    int w = blockIdx.x * 4 + (threadIdx.x >> 6);
    int lane = threadIdx.x & 63;
    int per = (N + waves_total - 1) / waves_total;
    int n0 = w * per;
    int n1 = min(N, n0 + per);
    if (n0 >= n1) return;
    int gcur = batch[n0];
    float2 acc = make_float2(0.f, 0.f);
    for (int i = n0; i < n1; ++i) {
        int g = batch[i];
        if (g != gcur) {
            atomicAdd(&gsum[gcur * DFEAT + lane * 2 + 0], acc.x);
            atomicAdd(&gsum[gcur * DFEAT + lane * 2 + 1], acc.y);
            acc = make_float2(0.f, 0.f);
            gcur = g;
        }
        float2 v = Hn[(size_t)i * 64 + lane];
        acc.x += v.x;
        acc.y += v.y;
    }
    atomicAdd(&gsum[gcur * DFEAT + lane * 2 + 0], acc.x);
    atomicAdd(&gsum[gcur * DFEAT + lane * 2 + 1], acc.y);
}

// Pool phase 2: divide by count (binary search on sorted batch), dot Wf, +bf.
__global__ __launch_bounds__(128) void k_head(const float* __restrict__ gsum,
                                              const int* __restrict__ batch,
                                              const float* __restrict__ Wf,
                                              const float* __restrict__ bf,
                                              float* __restrict__ out, int N) {
    int g = blockIdx.x;
    int tid = threadIdx.x;
    int l = 0, h = N;
    while (l < h) { int m = (l + h) >> 1; if (batch[m] < g) l = m + 1; else h = m; }
    int lo = l;
    h = N;
    while (l < h) { int m = (l + h) >> 1; if (batch[m] < g + 1) l = m + 1; else h = m; }
    int hi = l;
    float cnt = (float)((hi - lo) > 0 ? (hi - lo) : 1);
    float val = (gsum[g * DFEAT + tid] / cnt) * Wf[tid];
    for (int off = 32; off >= 1; off >>= 1) val += __shfl_down(val, off, 64);
    __shared__ float ws2[2];
    if ((tid & 63) == 0) ws2[tid >> 6] = val;
    __syncthreads();
    if (tid == 0) out[g] = ws2[0] + ws2[1] + bf[0];
}

extern "C" void kernel_launch(void* const* d_in, const int* in_sizes, int n_in,
                              void* d_out, int out_size, void* d_ws, size_t ws_size,
                              hipStream_t stream) {
    const float* x    = (const float*)d_in[0];
    const int*   ei   = (const int*)d_in[1];
    const int*   batch= (const int*)d_in[2];
    const float* W1   = (const float*)d_in[3];
    const float* b1   = (const float*)d_in[4];
    const float* W2   = (const float*)d_in[5];
    const float* b2   = (const float*)d_in[6];
    const float* Wf   = (const float*)d_in[7];
    const float* bf   = (const float*)d_in[8];

    int N = in_sizes[0] / DFEAT;
    int E = in_sizes[1] / 2;
    int G = out_size;  // num_graphs

    const int* src = ei;
    const int* dst = ei + E;

    char* wsb = (char*)d_ws;
    size_t off = 0;
    auto walloc = [&](size_t bytes) {
        void* p = wsb + off;
        off = (off + bytes + 255) & ~(size_t)255;
        return p;
    };
    uint32* A     = (uint32*)walloc((size_t)N * 64 * sizeof(uint32)); // bf16 table, 25.6 MB
    float* B      = (float*)walloc((size_t)N * DFEAT * sizeof(float)); // 51.2 MB
    float* dinv   = (float*)walloc((size_t)N * sizeof(float));
    int*   rowptr = (int*)  walloc((size_t)(N + 1) * sizeof(int));
    int*   col    = (int*)  walloc((size_t)E * sizeof(int));           // 6.4 MB
    int*   degcnt = (int*)  walloc((size_t)N * sizeof(int));
    int*   fill   = (int*)  walloc((size_t)N * sizeof(int));
    float* gsum   = (float*)walloc((size_t)G * DFEAT * sizeof(float)); // 32 KB
    int*   bsum   = (int*)  walloc((size_t)SCAN_NB * sizeof(int));
    (void)ws_size; (void)n_in;

    int gN = (N + 255) / 256;
    int gE = (E + 255) / 256;
    int chunk = (N + SCAN_NB - 1) / SCAN_NB;

    // CSR build
    k_zero2<<<gN, 256, 0, stream>>>(degcnt, fill, N);
    k_zero_f<<<(G * DFEAT + 255) / 256, 256, 0, stream>>>(gsum, G * DFEAT);
    k_degcount<<<gE, 256, 0, stream>>>(dst, degcnt, E);
    k_partsum<<<SCAN_NB, SCAN_TPB, 0, stream>>>(degcnt, bsum, N, chunk);
    k_scanb<<<1, SCAN_NB, 0, stream>>>(bsum);
    k_writeptr<<<SCAN_NB, SCAN_TPB, 0, stream>>>(degcnt, bsum, rowptr, dinv, N, chunk);
    k_fill<<<gE, 256, 0, stream>>>(src, dst, rowptr, fill, col, E);

    // layer 1
    k_linear<<<512, 256, 0, stream>>>(x, W1, A, N);
    k_agg<<<(N + 3) / 4, 256, 0, stream>>>(A, (float2*)B, col, rowptr, dinv, b1, N);
    // layer 2
    k_linear<<<512, 256, 0, stream>>>(B, W2, A, N);
    k_agg<<<(N + 3) / 4, 256, 0, stream>>>(A, (float2*)B, col, rowptr, dinv, b2, N);

    // pool + head
    const int POOL_BLOCKS = 1024;
    k_pool_sum<<<POOL_BLOCKS, 256, 0, stream>>>((const float2*)B, batch, gsum, N, POOL_BLOCKS * 4);
    k_head<<<G, 128, 0, stream>>>(gsum, batch, Wf, bf, (float*)d_out, N);
}

// Round 9
// 481.415 us; speedup vs baseline: 2.3185x; 1.0376x over previous
//
#include <hip/hip_runtime.h>
#include <hip/hip_bf16.h>
#include <math.h>

// GCN: h1 = relu(Agg(x@W1) + b1); h2 = relu(Agg(h1@W2) + b2);
// out[g] = mean_pool(h2)[g] @ Wf + bf
// Agg: symmetric deg^-1/2 norm with self-loops (PyG GCNConv default).
// CSR build once per call; pull-based aggregation (no fp atomics in hot path).
// R4: wave-sliced pool (395us -> ~15us). R5: decoupled scan (162us -> ~12us).
// R6: k_agg unroll x4. R7: bf16 feature table (gather bytes halved; 573->499).
// R8: k_fill dst-range-partitioned by blockIdx&7 (XCD %8 heuristic) to kill
//     write amplification (WRITE_SIZE was 107MB for a 6.4MB col array:
//     random 4B scatter from 8 incoherent L2s -> partial-line writebacks).

#define DFEAT 128
#define SCAN_NB 256
#define SCAN_TPB 256
#define FILL_CHUNKS 256

typedef unsigned int uint32;

__device__ __forceinline__ uint32 f2bf_rne(float f) {
    uint32 x = __float_as_uint(f);
    return (x + 0x7fffu + ((x >> 16) & 1u)) >> 16;
}
__device__ __forceinline__ uint32 packbf2(float lo, float hi) {
    return f2bf_rne(lo) | (f2bf_rne(hi) << 16);
}

__global__ void k_zero2(int* __restrict__ a, int* __restrict__ b, int n) {
    int i = blockIdx.x * blockDim.x + threadIdx.x;
    if (i < n) { a[i] = 0; b[i] = 0; }
}

__global__ void k_zero_f(float* __restrict__ p, int n) {
    int i = blockIdx.x * blockDim.x + threadIdx.x;
    if (i < n) p[i] = 0.f;
}

__global__ void k_degcount(const int* __restrict__ dst, int* __restrict__ degcnt, int E) {
    int e = blockIdx.x * blockDim.x + threadIdx.x;
    if (e < E) atomicAdd(&degcnt[dst[e]], 1);
}

// Scan phase 1: block b owns [b*chunk, ...); coalesced reads, LDS tree reduce.
__global__ __launch_bounds__(SCAN_TPB) void k_partsum(const int* __restrict__ deg,
                                                      int* __restrict__ bsum,
                                                      int N, int chunk) {
    int b = blockIdx.x, tid = threadIdx.x;
    int beg = b * chunk, end = min(N, beg + chunk);
    int s = 0;
    for (int i = beg + tid; i < end; i += SCAN_TPB) s += deg[i];
    __shared__ int lds[SCAN_TPB];
    lds[tid] = s;
    __syncthreads();
    for (int off = SCAN_TPB / 2; off > 0; off >>= 1) {
        if (tid < off) lds[tid] += lds[tid + off];
        __syncthreads();
    }
    if (tid == 0) bsum[b] = lds[0];
}

// Scan phase 2: single 256-thread block, exclusive scan of bsum in place.
__global__ __launch_bounds__(SCAN_NB) void k_scanb(int* __restrict__ bsum) {
    __shared__ int lds[SCAN_NB];
    int tid = threadIdx.x;
    int v = bsum[tid];
    lds[tid] = v;
    __syncthreads();
    for (int off = 1; off < SCAN_NB; off <<= 1) {
        int t = (tid >= off) ? lds[tid - off] : 0;
        __syncthreads();
        lds[tid] += t;
        __syncthreads();
    }
    bsum[tid] = lds[tid] - v;  // exclusive base
}

// Scan phase 3: per-thread sub-chunks, block scan, write rowptr (+dinv).
__global__ __launch_bounds__(SCAN_TPB) void k_writeptr(const int* __restrict__ deg,
                                                       const int* __restrict__ bbase,
                                                       int* __restrict__ rowptr,
                                                       float* __restrict__ dinv,
                                                       int N, int chunk) {
    int b = blockIdx.x, tid = threadIdx.x;
    int beg = b * chunk, end = min(N, beg + chunk);
    int per = (chunk + SCAN_TPB - 1) / SCAN_TPB;
    int tbeg = beg + tid * per;
    int tend = min(end, tbeg + per);
    int s = 0;
    for (int i = tbeg; i < tend; ++i) s += deg[i];
    __shared__ int lds[SCAN_TPB];
    lds[tid] = s;
    __syncthreads();
    for (int off = 1; off < SCAN_TPB; off <<= 1) {
        int t = (tid >= off) ? lds[tid - off] : 0;
        __syncthreads();
        lds[tid] += t;
        __syncthreads();
    }
    int run = bbase[b] + ((tid == 0) ? 0 : lds[tid - 1]);
    for (int i = tbeg; i < tend; ++i) {
        int d = deg[i];
        rowptr[i] = run;
        dinv[i] = rsqrtf((float)(d + 1));  // +1 self-loop
        run += d;
    }
    if (tend == N && tbeg < tend) rowptr[N] = run;  // == E
}

// CSR fill, dst-range partitioned: role r = blockIdx&7 handles dst ranges with
// ((d>>9)&7)==r. With round-robin block->XCD dispatch, all writes to a given
// col cache line come from one XCD's L2 -> full-line writebacks (~6.4MB not
// 107MB). Edges read 8x but L3-resident. Correct under ANY block placement.
__global__ __launch_bounds__(256) void k_fill(const int* __restrict__ src,
                                              const int* __restrict__ dst,
                                              const int* __restrict__ rowptr,
                                              int* __restrict__ fill,
                                              int* __restrict__ col, int E) {
    int r = blockIdx.x & 7;
    int chunk = blockIdx.x >> 3;
    int per = (E + FILL_CHUNKS - 1) / FILL_CHUNKS;
    int beg = chunk * per;
    int end = min(E, beg + per);
    for (int e = beg + threadIdx.x; e < end; e += 256) {
        int d = dst[e];
        if (((d >> 9) & 7) == r) {
            int pos = rowptr[d] + atomicAdd(&fill[d], 1);
            col[pos] = src[e];
        }
    }
}

// C[N,128] (bf16-packed) = H[N,128](f32) @ W[128,128](f32); W staged in LDS.
// Math in f32; output quantized RNE to bf16 (2 features per uint).
__global__ __launch_bounds__(256, 2) void k_linear(const float* __restrict__ H,
                                                   const float* __restrict__ W,
                                                   uint32* __restrict__ C, int N) {
    __shared__ float Wl[128 * 128];   // 64 KB
    __shared__ float inS[32 * 128];   // 16 KB
    int tid = threadIdx.x;
    {
        const float4* W4 = (const float4*)W;
        float4* Wl4 = (float4*)Wl;
#pragma unroll
        for (int j = 0; j < 16; ++j) Wl4[tid + j * 256] = W4[tid + j * 256];
    }
    int cg = tid & 31;
    int r0 = (tid >> 5) * 4;
    int ntiles = (N + 31) >> 5;
    const float4* WL4 = (const float4*)Wl;
    for (int tile = blockIdx.x; tile < ntiles; tile += gridDim.x) {
        int rbase = tile * 32;
        __syncthreads();
        {
            const float4* H4 = (const float4*)(H + (size_t)rbase * DFEAT);
            float4* I4 = (float4*)inS;
            int lim = (N - rbase) * 32;
#pragma unroll
            for (int j = 0; j < 4; ++j) {
                int idx = tid + j * 256;
                float4 v = make_float4(0.f, 0.f, 0.f, 0.f);
                if (idx < lim) v = H4[idx];
                I4[idx] = v;
            }
        }
        __syncthreads();
        float4 a0 = {0,0,0,0}, a1 = {0,0,0,0}, a2 = {0,0,0,0}, a3 = {0,0,0,0};
#pragma unroll 4
        for (int k = 0; k < 128; ++k) {
            float4 w = WL4[k * 32 + cg];
            float x0 = inS[(r0 + 0) * 128 + k];
            float x1 = inS[(r0 + 1) * 128 + k];
            float x2 = inS[(r0 + 2) * 128 + k];
            float x3 = inS[(r0 + 3) * 128 + k];
            a0.x += x0 * w.x; a0.y += x0 * w.y; a0.z += x0 * w.z; a0.w += x0 * w.w;
            a1.x += x1 * w.x; a1.y += x1 * w.y; a1.z += x1 * w.z; a1.w += x1 * w.w;
            a2.x += x2 * w.x; a2.y += x2 * w.y; a2.z += x2 * w.z; a2.w += x2 * w.w;
            a3.x += x3 * w.x; a3.y += x3 * w.y; a3.z += x3 * w.z; a3.w += x3 * w.w;
        }
        int row = rbase + r0;
        if (row + 0 < N) ((uint2*)(C + (size_t)(row + 0) * 64))[cg] = make_uint2(packbf2(a0.x, a0.y), packbf2(a0.z, a0.w));
        if (row + 1 < N) ((uint2*)(C + (size_t)(row + 1) * 64))[cg] = make_uint2(packbf2(a1.x, a1.y), packbf2(a1.z, a1.w));
        if (row + 2 < N) ((uint2*)(C + (size_t)(row + 2) * 64))[cg] = make_uint2(packbf2(a2.x, a2.y), packbf2(a2.z, a2.w));
        if (row + 3 < N) ((uint2*)(C + (size_t)(row + 3) * 64))[cg] = make_uint2(packbf2(a3.x, a3.y), packbf2(a3.z, a3.w));
    }
}

// Pull aggregation: one 64-lane wave per node; lane holds features 2*lane,2*lane+1.
// Gathers bf16-packed rows (256B/row), accumulates f32, writes f32.
__global__ __launch_bounds__(256) void k_agg(const uint32* __restrict__ Tb,
                                             float2* __restrict__ Hout,
                                             const int* __restrict__ col,
                                             const int* __restrict__ rowptr,
                                             const float* __restrict__ dinv,
                                             const float* __restrict__ bias, int N) {
    int lane = threadIdx.x & 63;
    int node = blockIdx.x * 4 + (threadIdx.x >> 6);
    if (node >= N) return;
    float2 b = ((const float2*)bias)[lane];
    float di = dinv[node];
    uint32 us = Tb[(size_t)node * 64 + lane];
    float ws = di * di;
    float2 acc;
    acc.x = __uint_as_float(us << 16) * ws;
    acc.y = __uint_as_float(us & 0xffff0000u) * ws;
    int beg = rowptr[node], end = rowptr[node + 1];
    int j = beg;
    for (; j + 3 < end; j += 4) {
        int s0 = col[j + 0];
        int s1 = col[j + 1];
        int s2 = col[j + 2];
        int s3 = col[j + 3];
        float w0 = dinv[s0] * di;
        float w1 = dinv[s1] * di;
        float w2 = dinv[s2] * di;
        float w3 = dinv[s3] * di;
        uint32 u0 = Tb[(size_t)s0 * 64 + lane];
        uint32 u1 = Tb[(size_t)s1 * 64 + lane];
        uint32 u2 = Tb[(size_t)s2 * 64 + lane];
        uint32 u3 = Tb[(size_t)s3 * 64 + lane];
        acc.x += w0 * __uint_as_float(u0 << 16);
        acc.y += w0 * __uint_as_float(u0 & 0xffff0000u);
        acc.x += w1 * __uint_as_float(u1 << 16);
        acc.y += w1 * __uint_as_float(u1 & 0xffff0000u);
        acc.x += w2 * __uint_as_float(u2 << 16);
        acc.y += w2 * __uint_as_float(u2 & 0xffff0000u);
        acc.x += w3 * __uint_as_float(u3 << 16);
        acc.y += w3 * __uint_as_float(u3 & 0xffff0000u);
    }
    for (; j < end; ++j) {
        int s = col[j];
        float w = dinv[s] * di;
        uint32 u = Tb[(size_t)s * 64 + lane];
        acc.x += w * __uint_as_float(u << 16);
        acc.y += w * __uint_as_float(u & 0xffff0000u);
    }
    acc.x = fmaxf(acc.x + b.x, 0.f);
    acc.y = fmaxf(acc.y + b.y, 0.f);
    Hout[(size_t)node * 64 + lane] = acc;
}

// Pool phase 1: wave-sliced partial sums, atomic flush at graph boundaries.
__global__ __launch_bounds__(256) void k_pool_sum(const float2* __restrict__ Hn,
                                                  const int* __restrict__ batch,
                                                  float* __restrict__ gsum,
                                                  int N, int waves_total) {
    int w = blockIdx.x * 4 + (threadIdx.x >> 6);
    int lane = threadIdx.x & 63;
    int per = (N + waves_total - 1) / waves_total;
    int n0 = w * per;
    int n1 = min(N, n0 + per);
    if (n0 >= n1) return;
    int gcur = batch[n0];
    float2 acc = make_float2(0.f, 0.f);
    for (int i = n0; i < n1; ++i) {
        int g = batch[i];
        if (g != gcur) {
            atomicAdd(&gsum[gcur * DFEAT + lane * 2 + 0], acc.x);
            atomicAdd(&gsum[gcur * DFEAT + lane * 2 + 1], acc.y);
            acc = make_float2(0.f, 0.f);
            gcur = g;
        }
        float2 v = Hn[(size_t)i * 64 + lane];
        acc.x += v.x;
        acc.y += v.y;
    }
    atomicAdd(&gsum[gcur * DFEAT + lane * 2 + 0], acc.x);
    atomicAdd(&gsum[gcur * DFEAT + lane * 2 + 1], acc.y);
}

// Pool phase 2: divide by count (binary search on sorted batch), dot Wf, +bf.
__global__ __launch_bounds__(128) void k_head(const float* __restrict__ gsum,
                                              const int* __restrict__ batch,
                                              const float* __restrict__ Wf,
                                              const float* __restrict__ bf,
                                              float* __restrict__ out, int N) {
    int g = blockIdx.x;
    int tid = threadIdx.x;
    int l = 0, h = N;
    while (l < h) { int m = (l + h) >> 1; if (batch[m] < g) l = m + 1; else h = m; }
    int lo = l;
    h = N;
    while (l < h) { int m = (l + h) >> 1; if (batch[m] < g + 1) l = m + 1; else h = m; }
    int hi = l;
    float cnt = (float)((hi - lo) > 0 ? (hi - lo) : 1);
    float val = (gsum[g * DFEAT + tid] / cnt) * Wf[tid];
    for (int off = 32; off >= 1; off >>= 1) val += __shfl_down(val, off, 64);
    __shared__ float ws2[2];
    if ((tid & 63) == 0) ws2[tid >> 6] = val;
    __syncthreads();
    if (tid == 0) out[g] = ws2[0] + ws2[1] + bf[0];
}

extern "C" void kernel_launch(void* const* d_in, const int* in_sizes, int n_in,
                              void* d_out, int out_size, void* d_ws, size_t ws_size,
                              hipStream_t stream) {
    const float* x    = (const float*)d_in[0];
    const int*   ei   = (const int*)d_in[1];
    const int*   batch= (const int*)d_in[2];
    const float* W1   = (const float*)d_in[3];
    const float* b1   = (const float*)d_in[4];
    const float* W2   = (const float*)d_in[5];
    const float* b2   = (const float*)d_in[6];
    const float* Wf   = (const float*)d_in[7];
    const float* bf   = (const float*)d_in[8];

    int N = in_sizes[0] / DFEAT;
    int E = in_sizes[1] / 2;
    int G = out_size;  // num_graphs

    const int* src = ei;
    const int* dst = ei + E;

    char* wsb = (char*)d_ws;
    size_t off = 0;
    auto walloc = [&](size_t bytes) {
        void* p = wsb + off;
        off = (off + bytes + 255) & ~(size_t)255;
        return p;
    };
    uint32* A     = (uint32*)walloc((size_t)N * 64 * sizeof(uint32)); // bf16 table, 25.6 MB
    float* B      = (float*)walloc((size_t)N * DFEAT * sizeof(float)); // 51.2 MB
    float* dinv   = (float*)walloc((size_t)N * sizeof(float));
    int*   rowptr = (int*)  walloc((size_t)(N + 1) * sizeof(int));
    int*   col    = (int*)  walloc((size_t)E * sizeof(int));           // 6.4 MB
    int*   degcnt = (int*)  walloc((size_t)N * sizeof(int));
    int*   fill   = (int*)  walloc((size_t)N * sizeof(int));
    float* gsum   = (float*)walloc((size_t)G * DFEAT * sizeof(float)); // 32 KB
    int*   bsum   = (int*)  walloc((size_t)SCAN_NB * sizeof(int));
    (void)ws_size; (void)n_in;

    int gN = (N + 255) / 256;
    int gE = (E + 255) / 256;
    int chunk = (N + SCAN_NB - 1) / SCAN_NB;

    // CSR build
    k_zero2<<<gN, 256, 0, stream>>>(degcnt, fill, N);
    k_zero_f<<<(G * DFEAT + 255) / 256, 256, 0, stream>>>(gsum, G * DFEAT);
    k_degcount<<<gE, 256, 0, stream>>>(dst, degcnt, E);
    k_partsum<<<SCAN_NB, SCAN_TPB, 0, stream>>>(degcnt, bsum, N, chunk);
    k_scanb<<<1, SCAN_NB, 0, stream>>>(bsum);
    k_writeptr<<<SCAN_NB, SCAN_TPB, 0, stream>>>(degcnt, bsum, rowptr, dinv, N, chunk);
    k_fill<<<FILL_CHUNKS * 8, 256, 0, stream>>>(src, dst, rowptr, fill, col, E);

    // layer 1
    k_linear<<<512, 256, 0, stream>>>(x, W1, A, N);
    k_agg<<<(N + 3) / 4, 256, 0, stream>>>(A, (float2*)B, col, rowptr, dinv, b1, N);
    // layer 2
    k_linear<<<512, 256, 0, stream>>>(B, W2, A, N);
    k_agg<<<(N + 3) / 4, 256, 0, stream>>>(A, (float2*)B, col, rowptr, dinv, b2, N);

    // pool + head
    const int POOL_BLOCKS = 1024;
    k_pool_sum<<<POOL_BLOCKS, 256, 0, stream>>>((const float2*)B, batch, gsum, N, POOL_BLOCKS * 4);
    k_head<<<G, 128, 0, stream>>>(gsum, batch, Wf, bf, (float*)d_out, N);
}

// Round 11
// 369.298 us; speedup vs baseline: 3.0224x; 1.3036x over previous
//
#include <hip/hip_runtime.h>
#include <hip/hip_bf16.h>
#include <math.h>

// GCN: h1 = relu(Agg(x@W1) + b1); h2 = relu(Agg(h1@W2) + b2);
// out[g] = mean_pool(h2)[g] @ Wf + bf
// Agg: symmetric deg^-1/2 norm with self-loops (PyG GCNConv default).
// CSR build once per call; pull-based aggregation (no fp atomics in hot path).
// R4: wave-sliced pool. R5: decoupled scan. R6: k_agg unroll x4.
// R7: bf16 feature table (gather bytes halved). R8: k_fill XCD-partitioned.
// R9: k_linear -> MFMA bf16. R10 FIX: WtS staging chunk decomposition was
//     n=c>>3/off=c&7 (8 uint4/row) but rows are 16 uint4 -> wrong addresses +
//     OOB LDS writes to ~64KB. Corrected to n=c>>4/off=c&15.

#define DFEAT 128
#define SCAN_NB 256
#define SCAN_TPB 256
#define FILL_CHUNKS 256

typedef unsigned int uint32;
typedef __attribute__((ext_vector_type(8))) short bf16x8;
typedef __attribute__((ext_vector_type(4))) float f32x4;

__device__ __forceinline__ uint32 f2bf_rne(float f) {
    uint32 x = __float_as_uint(f);
    return (x + 0x7fffu + ((x >> 16) & 1u)) >> 16;
}
__device__ __forceinline__ uint32 packbf2(float lo, float hi) {
    return f2bf_rne(lo) | (f2bf_rne(hi) << 16);
}

__global__ void k_zero2(int* __restrict__ a, int* __restrict__ b, int n) {
    int i = blockIdx.x * blockDim.x + threadIdx.x;
    if (i < n) { a[i] = 0; b[i] = 0; }
}

__global__ void k_zero_f(float* __restrict__ p, int n) {
    int i = blockIdx.x * blockDim.x + threadIdx.x;
    if (i < n) p[i] = 0.f;
}

__global__ void k_degcount(const int* __restrict__ dst, int* __restrict__ degcnt, int E) {
    int e = blockIdx.x * blockDim.x + threadIdx.x;
    if (e < E) atomicAdd(&degcnt[dst[e]], 1);
}

// W[k][n] f32 -> Wt[n][k] bf16 (one-time, 16K elements)
__global__ __launch_bounds__(256) void k_wt(const float* __restrict__ W,
                                            unsigned short* __restrict__ Wt) {
    int idx = blockIdx.x * 256 + threadIdx.x;
    if (idx < 128 * 128) {
        int n = idx >> 7, k = idx & 127;
        Wt[idx] = (unsigned short)f2bf_rne(W[(k << 7) + n]);
    }
}

// Scan phase 1
__global__ __launch_bounds__(SCAN_TPB) void k_partsum(const int* __restrict__ deg,
                                                      int* __restrict__ bsum,
                                                      int N, int chunk) {
    int b = blockIdx.x, tid = threadIdx.x;
    int beg = b * chunk, end = min(N, beg + chunk);
    int s = 0;
    for (int i = beg + tid; i < end; i += SCAN_TPB) s += deg[i];
    __shared__ int lds[SCAN_TPB];
    lds[tid] = s;
    __syncthreads();
    for (int off = SCAN_TPB / 2; off > 0; off >>= 1) {
        if (tid < off) lds[tid] += lds[tid + off];
        __syncthreads();
    }
    if (tid == 0) bsum[b] = lds[0];
}

// Scan phase 2
__global__ __launch_bounds__(SCAN_NB) void k_scanb(int* __restrict__ bsum) {
    __shared__ int lds[SCAN_NB];
    int tid = threadIdx.x;
    int v = bsum[tid];
    lds[tid] = v;
    __syncthreads();
    for (int off = 1; off < SCAN_NB; off <<= 1) {
        int t = (tid >= off) ? lds[tid - off] : 0;
        __syncthreads();
        lds[tid] += t;
        __syncthreads();
    }
    bsum[tid] = lds[tid] - v;  // exclusive base
}

// Scan phase 3: write rowptr + dinv
__global__ __launch_bounds__(SCAN_TPB) void k_writeptr(const int* __restrict__ deg,
                                                       const int* __restrict__ bbase,
                                                       int* __restrict__ rowptr,
                                                       float* __restrict__ dinv,
                                                       int N, int chunk) {
    int b = blockIdx.x, tid = threadIdx.x;
    int beg = b * chunk, end = min(N, beg + chunk);
    int per = (chunk + SCAN_TPB - 1) / SCAN_TPB;
    int tbeg = beg + tid * per;
    int tend = min(end, tbeg + per);
    int s = 0;
    for (int i = tbeg; i < tend; ++i) s += deg[i];
    __shared__ int lds[SCAN_TPB];
    lds[tid] = s;
    __syncthreads();
    for (int off = 1; off < SCAN_TPB; off <<= 1) {
        int t = (tid >= off) ? lds[tid - off] : 0;
        __syncthreads();
        lds[tid] += t;
        __syncthreads();
    }
    int run = bbase[b] + ((tid == 0) ? 0 : lds[tid - 1]);
    for (int i = tbeg; i < tend; ++i) {
        int d = deg[i];
        rowptr[i] = run;
        dinv[i] = rsqrtf((float)(d + 1));  // +1 self-loop
        run += d;
    }
    if (tend == N && tbeg < tend) rowptr[N] = run;  // == E
}

// CSR fill, dst-range partitioned (R8: kills partial-line writeback amp).
__global__ __launch_bounds__(256) void k_fill(const int* __restrict__ src,
                                              const int* __restrict__ dst,
                                              const int* __restrict__ rowptr,
                                              int* __restrict__ fill,
                                              int* __restrict__ col, int E) {
    int r = blockIdx.x & 7;
    int chunk = blockIdx.x >> 3;
    int per = (E + FILL_CHUNKS - 1) / FILL_CHUNKS;
    int beg = chunk * per;
    int end = min(E, beg + per);
    for (int e = beg + threadIdx.x; e < end; e += 256) {
        int d = dst[e];
        if (((d >> 9) & 7) == r) {
            int pos = rowptr[d] + atomicAdd(&fill[d], 1);
            col[pos] = src[e];
        }
    }
}

// C[N,128](bf16) = H[N,128](f32) @ W via Wt[n][k] bf16. MFMA 16x16x32.
// Swapped operands: A=Wt rows (M-dim = n), B=H rows (N-dim = m).
// Wave wv owns m-rows wv*16..+15 of the 64-row tile, all 8 n-tiles.
__global__ __launch_bounds__(256, 3) void k_linear_mfma(const float* __restrict__ H,
                                                        const uint32* __restrict__ Wt,
                                                        uint32* __restrict__ C,
                                                        int N, int ntiles) {
    __shared__ uint32 WtS[128 * 64];  // 32 KB, row n: 128 bf16 (k-contig), swizzled
    __shared__ uint32 inS[64 * 64];   // 16 KB, row m: 128 bf16 (k-contig), swizzled
    int tid = threadIdx.x;
    int lane = tid & 63;
    int wv = tid >> 6;       // 0..3
    int g = lane >> 4;       // k-group / reg-group
    int r = lane & 15;
    int swz = (r & 7) << 4;
    {   // stage Wt -> LDS: 2048 uint4 chunks, 16 per 256B row (R10 fix)
        const uint4* srcp = (const uint4*)Wt;
#pragma unroll
        for (int i = 0; i < 8; ++i) {
            int c = tid + i * 256;            // 0..2047
            int n = c >> 4, off = c & 15;
            int b = (n * 256 + off * 16) ^ ((n & 7) << 4);
            *(uint4*)((char*)WtS + b) = srcp[c];
        }
    }
    for (int t = blockIdx.x; t < ntiles; t += gridDim.x) {
        int rbase = t << 6;
        __syncthreads();  // protects WtS first use + inS vs prev iter reads
        {   // stage 64 H rows f32 -> bf16, swizzled
            const float4* H4 = (const float4*)(H + (size_t)rbase * DFEAT);
            int limrow = N - rbase;
#pragma unroll
            for (int i = 0; i < 4; ++i) {
                int c = tid + i * 256;        // 0..1023
                int m = c >> 4, off = c & 15;
                uint4 w2 = make_uint4(0u, 0u, 0u, 0u);
                if (m < limrow) {
                    float4 f0 = H4[m * 32 + off * 2];
                    float4 f1 = H4[m * 32 + off * 2 + 1];
                    w2.x = packbf2(f0.x, f0.y); w2.y = packbf2(f0.z, f0.w);
                    w2.z = packbf2(f1.x, f1.y); w2.w = packbf2(f1.z, f1.w);
                }
                int b = (m * 256 + off * 16) ^ ((m & 7) << 4);
                *(uint4*)((char*)inS + b) = w2;
            }
        }
        __syncthreads();
        f32x4 acc[8];
#pragma unroll
        for (int nt = 0; nt < 8; ++nt) acc[nt] = (f32x4){0.f, 0.f, 0.f, 0.f};
        int mrow = wv * 16 + r;
        const char* inB = (const char*)inS + mrow * 256;
#pragma unroll
        for (int kk = 0; kk < 4; ++kk) {
            int koff = (kk * 64 + g * 16) ^ swz;  // swizzled within-row byte off
            bf16x8 bfrag = *(const bf16x8*)(inB + koff);
#pragma unroll
            for (int nt = 0; nt < 8; ++nt) {
                bf16x8 afrag = *(const bf16x8*)((const char*)WtS + (nt * 16 + r) * 256 + koff);
                acc[nt] = __builtin_amdgcn_mfma_f32_16x16x32_bf16(afrag, bfrag, acc[nt], 0, 0, 0);
            }
        }
        int m = rbase + mrow;
        if (m < N) {
            uint2* Crow = (uint2*)(C + (size_t)m * 64);
#pragma unroll
            for (int nt = 0; nt < 8; ++nt) {
                uint2 u;
                u.x = packbf2(acc[nt].x, acc[nt].y);  // n = nt*16+g*4 + 0,1
                u.y = packbf2(acc[nt].z, acc[nt].w);  // n = nt*16+g*4 + 2,3
                Crow[nt * 4 + g] = u;
            }
        }
    }
}

// Pull aggregation: one 64-lane wave per node; bf16 gathers, f32 accum.
__global__ __launch_bounds__(256) void k_agg(const uint32* __restrict__ Tb,
                                             float2* __restrict__ Hout,
                                             const int* __restrict__ col,
                                             const int* __restrict__ rowptr,
                                             const float* __restrict__ dinv,
                                             const float* __restrict__ bias, int N) {
    int lane = threadIdx.x & 63;
    int node = blockIdx.x * 4 + (threadIdx.x >> 6);
    if (node >= N) return;
    float2 b = ((const float2*)bias)[lane];
    float di = dinv[node];
    uint32 us = Tb[(size_t)node * 64 + lane];
    float ws = di * di;
    float2 acc;
    acc.x = __uint_as_float(us << 16) * ws;
    acc.y = __uint_as_float(us & 0xffff0000u) * ws;
    int beg = rowptr[node], end = rowptr[node + 1];
    int j = beg;
    for (; j + 3 < end; j += 4) {
        int s0 = col[j + 0];
        int s1 = col[j + 1];
        int s2 = col[j + 2];
        int s3 = col[j + 3];
        float w0 = dinv[s0] * di;
        float w1 = dinv[s1] * di;
        float w2 = dinv[s2] * di;
        float w3 = dinv[s3] * di;
        uint32 u0 = Tb[(size_t)s0 * 64 + lane];
        uint32 u1 = Tb[(size_t)s1 * 64 + lane];
        uint32 u2 = Tb[(size_t)s2 * 64 + lane];
        uint32 u3 = Tb[(size_t)s3 * 64 + lane];
        acc.x += w0 * __uint_as_float(u0 << 16);
        acc.y += w0 * __uint_as_float(u0 & 0xffff0000u);
        acc.x += w1 * __uint_as_float(u1 << 16);
        acc.y += w1 * __uint_as_float(u1 & 0xffff0000u);
        acc.x += w2 * __uint_as_float(u2 << 16);
        acc.y += w2 * __uint_as_float(u2 & 0xffff0000u);
        acc.x += w3 * __uint_as_float(u3 << 16);
        acc.y += w3 * __uint_as_float(u3 & 0xffff0000u);
    }
    for (; j < end; ++j) {
        int s = col[j];
        float w = dinv[s] * di;
        uint32 u = Tb[(size_t)s * 64 + lane];
        acc.x += w * __uint_as_float(u << 16);
        acc.y += w * __uint_as_float(u & 0xffff0000u);
    }
    acc.x = fmaxf(acc.x + b.x, 0.f);
    acc.y = fmaxf(acc.y + b.y, 0.f);
    Hout[(size_t)node * 64 + lane] = acc;
}

// Pool phase 1: wave-sliced partial sums, atomic flush at graph boundaries.
__global__ __launch_bounds__(256) void k_pool_sum(const float2* __restrict__ Hn,
                                                  const int* __restrict__ batch,
                                                  float* __restrict__ gsum,
                                                  int N, int waves_total) {
    int w = blockIdx.x * 4 + (threadIdx.x >> 6);
    int lane = threadIdx.x & 63;
    int per = (N + waves_total - 1) / waves_total;
    int n0 = w * per;
    int n1 = min(N, n0 + per);
    if (n0 >= n1) return;
    int gcur = batch[n0];
    float2 acc = make_float2(0.f, 0.f);
    for (int i = n0; i < n1; ++i) {
        int g = batch[i];
        if (g != gcur) {
            atomicAdd(&gsum[gcur * DFEAT + lane * 2 + 0], acc.x);
            atomicAdd(&gsum[gcur * DFEAT + lane * 2 + 1], acc.y);
            acc = make_float2(0.f, 0.f);
            gcur = g;
        }
        float2 v = Hn[(size_t)i * 64 + lane];
        acc.x += v.x;
        acc.y += v.y;
    }
    atomicAdd(&gsum[gcur * DFEAT + lane * 2 + 0], acc.x);
    atomicAdd(&gsum[gcur * DFEAT + lane * 2 + 1], acc.y);
}

// Pool phase 2: divide by count, dot Wf, +bf.
__global__ __launch_bounds__(128) void k_head(const float* __restrict__ gsum,
                                              const int* __restrict__ batch,
                                              const float* __restrict__ Wf,
                                              const float* __restrict__ bf,
                                              float* __restrict__ out, int N) {
    int g = blockIdx.x;
    int tid = threadIdx.x;
    int l = 0, h = N;
    while (l < h) { int m = (l + h) >> 1; if (batch[m] < g) l = m + 1; else h = m; }
    int lo = l;
    h = N;
    while (l < h) { int m = (l + h) >> 1; if (batch[m] < g + 1) l = m + 1; else h = m; }
    int hi = l;
    float cnt = (float)((hi - lo) > 0 ? (hi - lo) : 1);
    float val = (gsum[g * DFEAT + tid] / cnt) * Wf[tid];
    for (int off = 32; off >= 1; off >>= 1) val += __shfl_down(val, off, 64);
    __shared__ float ws2[2];
    if ((tid & 63) == 0) ws2[tid >> 6] = val;
    __syncthreads();
    if (tid == 0) out[g] = ws2[0] + ws2[1] + bf[0];
}

extern "C" void kernel_launch(void* const* d_in, const int* in_sizes, int n_in,
                              void* d_out, int out_size, void* d_ws, size_t ws_size,
                              hipStream_t stream) {
    const float* x    = (const float*)d_in[0];
    const int*   ei   = (const int*)d_in[1];
    const int*   batch= (const int*)d_in[2];
    const float* W1   = (const float*)d_in[3];
    const float* b1   = (const float*)d_in[4];
    const float* W2   = (const float*)d_in[5];
    const float* b2   = (const float*)d_in[6];
    const float* Wf   = (const float*)d_in[7];
    const float* bf   = (const float*)d_in[8];

    int N = in_sizes[0] / DFEAT;
    int E = in_sizes[1] / 2;
    int G = out_size;  // num_graphs

    const int* src = ei;
    const int* dst = ei + E;

    char* wsb = (char*)d_ws;
    size_t off = 0;
    auto walloc = [&](size_t bytes) {
        void* p = wsb + off;
        off = (off + bytes + 255) & ~(size_t)255;
        return p;
    };
    uint32* A     = (uint32*)walloc((size_t)N * 64 * sizeof(uint32)); // bf16 table, 25.6 MB
    float* B      = (float*)walloc((size_t)N * DFEAT * sizeof(float)); // 51.2 MB
    float* dinv   = (float*)walloc((size_t)N * sizeof(float));
    int*   rowptr = (int*)  walloc((size_t)(N + 1) * sizeof(int));
    int*   col    = (int*)  walloc((size_t)E * sizeof(int));           // 6.4 MB
    int*   degcnt = (int*)  walloc((size_t)N * sizeof(int));
    int*   fill   = (int*)  walloc((size_t)N * sizeof(int));
    float* gsum   = (float*)walloc((size_t)G * DFEAT * sizeof(float)); // 32 KB
    int*   bsum   = (int*)  walloc((size_t)SCAN_NB * sizeof(int));
    unsigned short* Wt1 = (unsigned short*)walloc(128 * 128 * sizeof(unsigned short));
    unsigned short* Wt2 = (unsigned short*)walloc(128 * 128 * sizeof(unsigned short));
    (void)ws_size; (void)n_in;

    int gN = (N + 255) / 256;
    int gE = (E + 255) / 256;
    int chunk = (N + SCAN_NB - 1) / SCAN_NB;
    int ntiles = (N + 63) >> 6;

    // CSR build + weight transposes
    k_zero2<<<gN, 256, 0, stream>>>(degcnt, fill, N);
    k_zero_f<<<(G * DFEAT + 255) / 256, 256, 0, stream>>>(gsum, G * DFEAT);
    k_wt<<<64, 256, 0, stream>>>(W1, Wt1);
    k_wt<<<64, 256, 0, stream>>>(W2, Wt2);
    k_degcount<<<gE, 256, 0, stream>>>(dst, degcnt, E);
    k_partsum<<<SCAN_NB, SCAN_TPB, 0, stream>>>(degcnt, bsum, N, chunk);
    k_scanb<<<1, SCAN_NB, 0, stream>>>(bsum);
    k_writeptr<<<SCAN_NB, SCAN_TPB, 0, stream>>>(degcnt, bsum, rowptr, dinv, N, chunk);
    k_fill<<<FILL_CHUNKS * 8, 256, 0, stream>>>(src, dst, rowptr, fill, col, E);

    // layer 1
    k_linear_mfma<<<768, 256, 0, stream>>>(x, (const uint32*)Wt1, A, N, ntiles);
    k_agg<<<(N + 3) / 4, 256, 0, stream>>>(A, (float2*)B, col, rowptr, dinv, b1, N);
    // layer 2
    k_linear_mfma<<<768, 256, 0, stream>>>(B, (const uint32*)Wt2, A, N, ntiles);
    k_agg<<<(N + 3) / 4, 256, 0, stream>>>(A, (float2*)B, col, rowptr, dinv, b2, N);

    // pool + head
    const int POOL_BLOCKS = 1024;
    k_pool_sum<<<POOL_BLOCKS, 256, 0, stream>>>((const float2*)B, batch, gsum, N, POOL_BLOCKS * 4);
    k_head<<<G, 128, 0, stream>>>(gsum, batch, Wf, bf, (float*)d_out, N);
}